// Round 12
// baseline (253.534 us; speedup 1.0000x reference)
//
#include <hip/hip_runtime.h>
#include <cstdint>

#define NN    1024
#define MM    32
#define NEDGE 32240
#define MROWS 64480   // 2*NEDGE
#define PX    168     // X tile pitch (ushorts)
#define PST   392     // unified stage pitch: 256 (H1n) + 128 (H1e) + 8 pad

typedef unsigned short ushort_t;

typedef __bf16 bf16x8 __attribute__((ext_vector_type(8)));
typedef float  floatx4 __attribute__((ext_vector_type(4)));

__device__ __forceinline__ float b2f(ushort_t u) {
    union { unsigned int i; float f; } v; v.i = ((unsigned int)u) << 16; return v.f;
}
__device__ __forceinline__ ushort_t f2b(float f) {
    unsigned int u = __builtin_bit_cast(unsigned int, f);
    u = (u + 0x7FFFu + ((u >> 16) & 1u)) >> 16;
    return (ushort_t)u;
}
// K(i): number of edges before node i
__device__ __forceinline__ int edge_base(int i) {
    return (i <= MM) ? ((i * (i - 1)) >> 1) : (496 + (i - MM) * MM);
}
// edge id e -> (dest i, src j)   [validated round 3; used only in pack]
__device__ __forceinline__ void edge_ij(int e, int& i, int& j) {
    if (e < 496) {
        i = (int)((1.0f + sqrtf(8.0f * (float)e + 1.0f)) * 0.5f);
        while (((i * (i - 1)) >> 1) > e) --i;
        while (((i * (i + 1)) >> 1) <= e) ++i;
        j = e - ((i * (i - 1)) >> 1);
    } else {
        int q = e - 496;
        i = MM + (q >> 5);
        j = i - MM + (q & 31);
    }
}

// ---------------- pack: weight transpose + nodes/edges bf16 + ij table (unchanged R11) ----------------
__global__ __launch_bounds__(256) void k_pack(
        const float* an1, const float* an2, const float* ae1, const float* ae2,
        const float* le1, const float* le2, const float* ln1, const float* ln2,
        const float* nodes, const float* edges,
        ushort_t* pan1, ushort_t* pan2, ushort_t* pae1, ushort_t* pae2,
        ushort_t* ple1, ushort_t* ple2, ushort_t* pln1, ushort_t* pln2,
        ushort_t* nodesb, ushort_t* edgesb, int2* ijt) {
    __shared__ float tile[32][33];
    const int bid = blockIdx.x;
    const int tid = threadIdx.x;
    if (bid < 152) {
        const float* s; ushort_t* d; int K, N, t;
        if (bid < 40)       { s = an1; d = pan1; K = 160; N = 256; t = bid;       }
        else if (bid < 72)  { s = an2; d = pan2; K = 256; N = 128; t = bid - 40;  }
        else if (bid < 84)  { s = ae1; d = pae1; K = 96;  N = 128; t = bid - 72;  }
        else if (bid < 92)  { s = ae2; d = pae2; K = 128; N = 64;  t = bid - 84;  }
        else if (bid < 101) { s = le1; d = ple1; K = 96;  N = 96;  t = bid - 92;  }
        else if (bid < 104) { s = le2; d = ple2; K = 96;  N = 32;  t = bid - 101; }
        else if (bid < 140) { s = ln1; d = pln1; K = 192; N = 192; t = bid - 104; }
        else                { s = ln2; d = pln2; K = 192; N = 64;  t = bid - 140; }
        int ntn = N >> 5;
        int tk = t / ntn, tn = t - tk * ntn;
        int k0 = tk * 32, n0 = tn * 32;
        int tx = tid & 31, ty = tid >> 5;
#pragma unroll
        for (int m = 0; m < 4; ++m)
            tile[ty + m * 8][tx] = s[(size_t)(k0 + ty + m * 8) * N + n0 + tx];
        __syncthreads();
#pragma unroll
        for (int m = 0; m < 4; ++m)
            d[(size_t)(n0 + ty + m * 8) * K + k0 + tx] = f2b(tile[tx][ty + m * 8]);
    } else if (bid < 280) {
        int i4 = (bid - 152) * 256 + tid;
        float4 v = ((const float4*)nodes)[i4];
        uint2 o;
        o.x = (unsigned)f2b(v.x) | ((unsigned)f2b(v.y) << 16);
        o.y = (unsigned)f2b(v.z) | ((unsigned)f2b(v.w) << 16);
        ((uint2*)nodesb)[i4] = o;
    } else if (bid < 2296) {
        int i4 = (bid - 280) * 256 + tid;
        if (i4 < 515840) {
            float4 v = ((const float4*)edges)[i4];
            uint2 o;
            o.x = (unsigned)f2b(v.x) | ((unsigned)f2b(v.y) << 16);
            o.y = (unsigned)f2b(v.z) | ((unsigned)f2b(v.w) << 16);
            ((uint2*)edgesb)[i4] = o;
        }
    } else {
        int e = (bid - 2296) * 256 + tid;
        if (e < NEDGE) { int i, j; edge_ij(e, i, j); ijt[e] = make_int2(i, j); }
    }
}

// ---------------- agg: merged node+edge branches (unchanged R11 — best measured variant) ----------------
__global__ __launch_bounds__(512, 2) void k_agg(
        const ushort_t* __restrict__ nodesb, const ushort_t* __restrict__ edgesb,
        const int2* __restrict__ ijt,
        const ushort_t* __restrict__ pan1, const float* __restrict__ ban1,
        const ushort_t* __restrict__ pan2, const float* __restrict__ ban2,
        const ushort_t* __restrict__ pae1, const float* __restrict__ bae1,
        const ushort_t* __restrict__ pae2, const float* __restrict__ bae2,
        ushort_t* __restrict__ hn, ushort_t* __restrict__ he) {
    __shared__ alignas(16) ushort_t X[32 * PX];     // X tile; reused as hn-stage (pitch 136)
    __shared__ alignas(16) ushort_t H[32 * PST];    // H1 tile; reused as he-stage (pitch 72)
    const int tid = threadIdx.x;
    const int w = tid >> 6, l = tid & 63, lrow = l & 15, lq = l >> 4;
    const int mt = blockIdx.x;
    floatx4 zero = {0.f, 0.f, 0.f, 0.f};

    bf16x8 B0[5], B1[5], B2[3];
#pragma unroll
    for (int kt = 0; kt < 5; ++kt) {
        B0[kt] = *(const bf16x8*)(pan1 + (size_t)(16 * w + lrow) * 160 + kt * 32 + lq * 8);
        B1[kt] = *(const bf16x8*)(pan1 + (size_t)(16 * (w + 8) + lrow) * 160 + kt * 32 + lq * 8);
    }
#pragma unroll
    for (int kt = 0; kt < 3; ++kt)
        B2[kt] = *(const bf16x8*)(pae1 + (size_t)(16 * w + lrow) * 96 + kt * 32 + lq * 8);
    float c0 = ban1[16 * w + lrow];
    float c1 = ban1[16 * (w + 8) + lrow];
    float c2 = bae1[16 * w + lrow];

#pragma unroll
    for (int k = 0; k < 4; ++k) {
        int rr = w * 4 + k;
        int r = mt * 32 + rr;
        int off = (r >= NEDGE) ? 1 : 0;
        int2 ij = ijt[r - off * NEDGE];
        int bN = off * NN;
        unsigned* xr = (unsigned*)(X + rr * PX);
        const unsigned* nj = (const unsigned*)(nodesb + (size_t)(bN + ij.y) * 64);
        const unsigned* ni = (const unsigned*)(nodesb + (size_t)(bN + ij.x) * 64);
        const unsigned* eb = (const unsigned*)(edgesb + (size_t)r * 32);
        if (l < 32) { xr[l] = nj[l]; xr[48 + l] = ni[l]; }
        else        xr[l] = eb[l - 32];
    }
    __syncthreads();

#pragma unroll
    for (int s = 0; s < 2; ++s) {
        bf16x8 A[5];
#pragma unroll
        for (int kt = 0; kt < 5; ++kt)
            A[kt] = *(const bf16x8*)&X[(s * 16 + lrow) * PX + kt * 32 + lq * 8];
        floatx4 a0 = zero, a1 = zero, a2 = zero;
#pragma unroll
        for (int kt = 0; kt < 5; ++kt) {
            a0 = __builtin_amdgcn_mfma_f32_16x16x32_bf16(A[kt], B0[kt], a0, 0, 0, 0);
            a1 = __builtin_amdgcn_mfma_f32_16x16x32_bf16(A[kt], B1[kt], a1, 0, 0, 0);
        }
#pragma unroll
        for (int kt = 0; kt < 3; ++kt)
            a2 = __builtin_amdgcn_mfma_f32_16x16x32_bf16(A[kt], B2[kt], a2, 0, 0, 0);
#pragma unroll
        for (int r_ = 0; r_ < 4; ++r_) {
            int row = (s * 16 + lq * 4 + r_) * PST;
            H[row + 16 * w + lrow]       = f2b(fmaxf(a0[r_] + c0, 0.f));
            H[row + 128 + 16 * w + lrow] = f2b(fmaxf(a1[r_] + c1, 0.f));
            H[row + 256 + 16 * w + lrow] = f2b(fmaxf(a2[r_] + c2, 0.f));
        }
    }
    __syncthreads();

    floatx4 o0[2], o1[2];
    if (w < 4) {
        bf16x8 D0[8], D1[8];
#pragma unroll
        for (int kt = 0; kt < 8; ++kt) {
            D0[kt] = *(const bf16x8*)(pan2 + (size_t)(16 * w + lrow) * 256 + kt * 32 + lq * 8);
            D1[kt] = *(const bf16x8*)(pan2 + (size_t)(16 * (w + 4) + lrow) * 256 + kt * 32 + lq * 8);
        }
        float d0 = ban2[16 * w + lrow];
        float d1 = ban2[16 * (w + 4) + lrow];
#pragma unroll
        for (int s = 0; s < 2; ++s) {
            floatx4 a0 = zero, a1 = zero;
#pragma unroll
            for (int kt = 0; kt < 8; ++kt) {
                bf16x8 a = *(const bf16x8*)&H[(s * 16 + lrow) * PST + kt * 32 + lq * 8];
                a0 = __builtin_amdgcn_mfma_f32_16x16x32_bf16(a, D0[kt], a0, 0, 0, 0);
                a1 = __builtin_amdgcn_mfma_f32_16x16x32_bf16(a, D1[kt], a1, 0, 0, 0);
            }
#pragma unroll
            for (int r_ = 0; r_ < 4; ++r_) { o0[s][r_] = a0[r_] + d0; o1[s][r_] = a1[r_] + d1; }
        }
    } else {
        int u = w - 4;
        bf16x8 E[4];
#pragma unroll
        for (int kt = 0; kt < 4; ++kt)
            E[kt] = *(const bf16x8*)(pae2 + (size_t)(16 * u + lrow) * 128 + kt * 32 + lq * 8);
        float d2 = bae2[16 * u + lrow];
#pragma unroll
        for (int s = 0; s < 2; ++s) {
            floatx4 a2 = zero;
#pragma unroll
            for (int kt = 0; kt < 4; ++kt) {
                bf16x8 a = *(const bf16x8*)&H[(s * 16 + lrow) * PST + 256 + kt * 32 + lq * 8];
                a2 = __builtin_amdgcn_mfma_f32_16x16x32_bf16(a, E[kt], a2, 0, 0, 0);
            }
#pragma unroll
            for (int r_ = 0; r_ < 4; ++r_) o0[s][r_] = a2[r_] + d2;
        }
    }
    __syncthreads();

    ushort_t* S = X;
    ushort_t* T = H;
    if (w < 4) {
#pragma unroll
        for (int s = 0; s < 2; ++s)
#pragma unroll
            for (int r_ = 0; r_ < 4; ++r_) {
                int row = (s * 16 + lq * 4 + r_) * 136;
                S[row + 16 * w + lrow]        = f2b(fmaxf(o0[s][r_], 0.f));
                S[row + 64 + 16 * w + lrow]   = f2b(fmaxf(o1[s][r_], 0.f));
            }
    } else {
        int u = w - 4;
#pragma unroll
        for (int s = 0; s < 2; ++s)
#pragma unroll
            for (int r_ = 0; r_ < 4; ++r_)
                T[(s * 16 + lq * 4 + r_) * 72 + 16 * u + lrow] = f2b(fmaxf(o0[s][r_], 0.f));
    }
    __syncthreads();

    {
        int row = tid >> 4, c = tid & 15;
        ((uint4*)(hn + (size_t)(mt * 32 + row) * 128))[c] = *(const uint4*)&S[row * 136 + c * 8];
        if (tid < 256) {
            int row2 = tid >> 3, c2 = tid & 7;
            ((uint4*)(he + (size_t)(mt * 32 + row2) * 64))[c2] = *(const uint4*)&T[row2 * 72 + c2 * 8];
        }
    }
}

// ---------------- fin: fused mid+final. Node blocks [0,64): pn-from-hn + MLP. Edge blocks: prefix + le12 ----------------
__global__ __launch_bounds__(192) void k_fin(
        const ushort_t* __restrict__ hn, const ushort_t* __restrict__ he,
        const ushort_t* __restrict__ nodesb, const ushort_t* __restrict__ edgesb,
        const int2* __restrict__ ijt,
        const ushort_t* __restrict__ pln1, const float* __restrict__ bln1,
        const ushort_t* __restrict__ pln2, const float* __restrict__ bln2,
        float* __restrict__ out_nodes,
        const ushort_t* __restrict__ ple1, const float* __restrict__ ble1,
        const ushort_t* __restrict__ ple2, const float* __restrict__ ble2,
        float* __restrict__ out_edges) {
    __shared__ alignas(16) ushort_t LA[32 * 200];
    __shared__ alignas(16) ushort_t LB[32 * 200];   // edge path: first 63*64 aliased as he-window
    __shared__ int pmeta[32];
    const int tid = threadIdx.x;
    const int w = tid >> 6, l = tid & 63, lrow = l & 15, lq = l >> 4;
    floatx4 zero = {0.f, 0.f, 0.f, 0.f};

    if (blockIdx.x < 64) {
        // ---- node path: compute pn rows in-block (fused k_mid), then MLP 192->192->64 ----
        int tile = blockIdx.x;
        for (int n = w; n < 32; n += 3) {           // wave per node, 11/11/10 split
            int ri = tile * 32 + n;
            int b = ri >> 10, i = ri & 1023;
            int t = min(i, MM);
            int base = b * NEDGE + edge_base(i);
            const unsigned* hp = (const unsigned*)(hn + (size_t)base * 128) + l;
            float s0 = 0.f, s1 = 0.f;
            for (int p = 0; p < t; ++p) {
                unsigned u = hp[(size_t)p * 64];
                s0 += b2f((ushort_t)(u & 0xffff));
                s1 += b2f((ushort_t)(u >> 16));
            }
            float inv = 1.0f / (float)max(t, 1);
            ((unsigned*)&LA[n * 200])[l] = (unsigned)f2b(s0 * inv) | ((unsigned)f2b(s1 * inv) << 16);
            if (l < 32)
                ((unsigned*)&LA[n * 200 + 128])[l] = ((const unsigned*)(nodesb + (size_t)ri * 64))[l];
        }
        bf16x8 f1[6][4]; float v1[4];
#pragma unroll
        for (int kt = 0; kt < 6; ++kt)
#pragma unroll
            for (int nt = 0; nt < 4; ++nt)
                f1[kt][nt] = *(const bf16x8*)(pln1 + (size_t)(w * 64 + nt * 16 + lrow) * 192 + kt * 32 + lq * 8);
#pragma unroll
        for (int nt = 0; nt < 4; ++nt) v1[nt] = bln1[w * 64 + nt * 16 + lrow];
        __syncthreads();

        floatx4 acc[2][4];
#pragma unroll
        for (int s = 0; s < 2; ++s)
#pragma unroll
            for (int nt = 0; nt < 4; ++nt) acc[s][nt] = zero;
#pragma unroll
        for (int s = 0; s < 2; ++s)
#pragma unroll
            for (int kt = 0; kt < 6; ++kt) {
                bf16x8 a = *(const bf16x8*)&LA[(s * 16 + lrow) * 200 + kt * 32 + lq * 8];
#pragma unroll
                for (int nt = 0; nt < 4; ++nt)
                    acc[s][nt] = __builtin_amdgcn_mfma_f32_16x16x32_bf16(a, f1[kt][nt], acc[s][nt], 0, 0, 0);
            }
#pragma unroll
        for (int s = 0; s < 2; ++s)
#pragma unroll
            for (int nt = 0; nt < 4; ++nt) {
                int col = w * 64 + nt * 16 + lrow;
#pragma unroll
                for (int r_ = 0; r_ < 4; ++r_)
                    LB[(s * 16 + lq * 4 + r_) * 200 + col] = f2b(fmaxf(acc[s][nt][r_] + v1[nt], 0.f));
            }
        bf16x8 f2[6][2]; float v2[2] = {0.f, 0.f};
        if (w < 2) {
#pragma unroll
            for (int kt = 0; kt < 6; ++kt)
#pragma unroll
                for (int nt = 0; nt < 2; ++nt)
                    f2[kt][nt] = *(const bf16x8*)(pln2 + (size_t)(w * 32 + nt * 16 + lrow) * 192 + kt * 32 + lq * 8);
#pragma unroll
            for (int nt = 0; nt < 2; ++nt) v2[nt] = bln2[w * 32 + nt * 16 + lrow];
        }
        __syncthreads();
        if (w < 2) {
            floatx4 a2[2][2];
#pragma unroll
            for (int s = 0; s < 2; ++s) { a2[s][0] = zero; a2[s][1] = zero; }
#pragma unroll
            for (int s = 0; s < 2; ++s)
#pragma unroll
                for (int kt = 0; kt < 6; ++kt) {
                    bf16x8 a = *(const bf16x8*)&LB[(s * 16 + lrow) * 200 + kt * 32 + lq * 8];
#pragma unroll
                    for (int nt = 0; nt < 2; ++nt)
                        a2[s][nt] = __builtin_amdgcn_mfma_f32_16x16x32_bf16(a, f2[kt][nt], a2[s][nt], 0, 0, 0);
                }
#pragma unroll
            for (int s = 0; s < 2; ++s)
#pragma unroll
                for (int nt = 0; nt < 2; ++nt) {
                    int col = w * 32 + nt * 16 + lrow;
#pragma unroll
                    for (int r_ = 0; r_ < 4; ++r_)
                        out_nodes[(size_t)(blockIdx.x * 32 + s * 16 + lq * 4 + r_) * 64 + col] =
                            fmaxf(a2[s][nt][r_] + v2[nt], 0.f);
                }
        }
    } else {
        // ---- edge path: fused prefix (from he span) + le12 ----
        int mt = blockIdx.x - 64;
        int r0 = mt * 32;
        int lo = max(r0 - 31, 0);
        int nrows = r0 + 32 - lo;                   // <= 63
        ushort_t* HW = LB;                          // he window [nrows][64], dead before LB reuse
        for (int u = tid; u < nrows * 8; u += 192)
            ((uint4*)HW)[u] = ((const uint4*)(he + (size_t)lo * 64))[u];
        // per-row window position p
        if (tid < 32) {
            int r = r0 + tid;
            int off = (r >= NEDGE) ? 1 : 0;
            int e = r - off * NEDGE;
            pmeta[tid] = e - edge_base(ijt[e].x);
        }
        // stage edge cols 64..95 of LA (pitch 104)
        for (int u = tid; u < 128; u += 192) {
            int row = u >> 2, c = u & 3;
            *(uint4*)&LA[row * 104 + 64 + c * 8] = ((const uint4*)(edgesb + (size_t)(r0 + row) * 32))[c];
        }
        bf16x8 fb1[3][2]; float v1[2];
#pragma unroll
        for (int kt = 0; kt < 3; ++kt)
#pragma unroll
            for (int nt = 0; nt < 2; ++nt)
                fb1[kt][nt] = *(const bf16x8*)(ple1 + (size_t)(w * 32 + nt * 16 + lrow) * 96 + kt * 32 + lq * 8);
#pragma unroll
        for (int nt = 0; nt < 2; ++nt) v1[nt] = ble1[w * 32 + nt * 16 + lrow];
        bf16x8 fb2[3]; float v2 = 0.f;
        if (w < 2) {
#pragma unroll
            for (int kt = 0; kt < 3; ++kt)
                fb2[kt] = *(const bf16x8*)(ple2 + (size_t)(w * 16 + lrow) * 96 + kt * 32 + lq * 8);
            v2 = ble2[w * 16 + lrow];
        }
        __syncthreads();

        // serial prefix on LDS (thread c = column), catch-up for rows before r0
        if (tid < 64) {
            int c = tid;
            int p0 = pmeta[0];
            float run = 0.f;
            for (int q = r0 - p0 - lo; q < r0 - lo; ++q) run += b2f(HW[q * 64 + c]);
            for (int k = 0; k < 32; ++k) {
                int p = pmeta[k];
                float v;
                if (p == 0) { run = 0.f; v = 0.f; }
                else v = run / (float)p;
                LA[k * 104 + c] = f2b(v);
                run += b2f(HW[(r0 + k - lo) * 64 + c]);
            }
        }
        __syncthreads();

        floatx4 acc[2][2];
#pragma unroll
        for (int s = 0; s < 2; ++s) { acc[s][0] = zero; acc[s][1] = zero; }
#pragma unroll
        for (int s = 0; s < 2; ++s)
#pragma unroll
            for (int kt = 0; kt < 3; ++kt) {
                bf16x8 a = *(const bf16x8*)&LA[(s * 16 + lrow) * 104 + kt * 32 + lq * 8];
#pragma unroll
                for (int nt = 0; nt < 2; ++nt)
                    acc[s][nt] = __builtin_amdgcn_mfma_f32_16x16x32_bf16(a, fb1[kt][nt], acc[s][nt], 0, 0, 0);
            }
        __syncthreads();                             // HW reads done; LB reusable
#pragma unroll
        for (int s = 0; s < 2; ++s)
#pragma unroll
            for (int nt = 0; nt < 2; ++nt) {
                int col = w * 32 + nt * 16 + lrow;
#pragma unroll
                for (int r_ = 0; r_ < 4; ++r_)
                    LB[(s * 16 + lq * 4 + r_) * 104 + col] = f2b(fmaxf(acc[s][nt][r_] + v1[nt], 0.f));
            }
        __syncthreads();
        if (w < 2) {
            floatx4 a2[2] = {zero, zero};
#pragma unroll
            for (int s = 0; s < 2; ++s)
#pragma unroll
                for (int kt = 0; kt < 3; ++kt) {
                    bf16x8 a = *(const bf16x8*)&LB[(s * 16 + lrow) * 104 + kt * 32 + lq * 8];
                    a2[s] = __builtin_amdgcn_mfma_f32_16x16x32_bf16(a, fb2[kt], a2[s], 0, 0, 0);
                }
#pragma unroll
            for (int s = 0; s < 2; ++s) {
                int col = w * 16 + lrow;
#pragma unroll
                for (int r_ = 0; r_ < 4; ++r_)
                    out_edges[(size_t)(mt * 32 + s * 16 + lq * 4 + r_) * 32 + col] = fmaxf(a2[s][r_] + v2, 0.f);
            }
        }
    }
}

extern "C" void kernel_launch(void* const* d_in, const int* in_sizes, int n_in,
                              void* d_out, int out_size, void* d_ws, size_t ws_size,
                              hipStream_t stream) {
    const float* nodes = (const float*)d_in[0];
    const float* edges = (const float*)d_in[1];
    const float* Wan1 = (const float*)d_in[2];  const float* ban1 = (const float*)d_in[3];
    const float* Wan2 = (const float*)d_in[4];  const float* ban2 = (const float*)d_in[5];
    const float* Wln1 = (const float*)d_in[6];  const float* bln1 = (const float*)d_in[7];
    const float* Wln2 = (const float*)d_in[8];  const float* bln2 = (const float*)d_in[9];
    const float* Wae1 = (const float*)d_in[10]; const float* bae1 = (const float*)d_in[11];
    const float* Wae2 = (const float*)d_in[12]; const float* bae2 = (const float*)d_in[13];
    const float* Wle1 = (const float*)d_in[14]; const float* ble1 = (const float*)d_in[15];
    const float* Wle2 = (const float*)d_in[16]; const float* ble2 = (const float*)d_in[17];

    char* ws = (char*)d_ws;
    size_t o = 0;
    auto alloc = [&](size_t bytes) -> void* {
        void* r = ws + o;
        o += (bytes + 255) & ~(size_t)255;
        return r;
    };
    ushort_t* hn     = (ushort_t*)alloc((size_t)MROWS * 128 * 2);
    ushort_t* he     = (ushort_t*)alloc((size_t)MROWS * 64 * 2);
    ushort_t* nodesb = (ushort_t*)alloc((size_t)2 * NN * 64 * 2);
    ushort_t* edgesb = (ushort_t*)alloc((size_t)MROWS * 32 * 2);
    int2*     ijt    = (int2*)alloc((size_t)NEDGE * 8);
    ushort_t* pan1 = (ushort_t*)alloc(160 * 256 * 2);
    ushort_t* pan2 = (ushort_t*)alloc(256 * 128 * 2);
    ushort_t* pae1 = (ushort_t*)alloc(96 * 128 * 2);
    ushort_t* pae2 = (ushort_t*)alloc(128 * 64 * 2);
    ushort_t* ple1 = (ushort_t*)alloc(96 * 96 * 2);
    ushort_t* ple2 = (ushort_t*)alloc(96 * 32 * 2);
    ushort_t* pln1 = (ushort_t*)alloc(192 * 192 * 2);
    ushort_t* pln2 = (ushort_t*)alloc(192 * 64 * 2);

    float* out_nodes = (float*)d_out;
    float* out_edges = (float*)d_out + 2 * NN * 64;

    k_pack<<<2422, 256, 0, stream>>>(Wan1, Wan2, Wae1, Wae2, Wle1, Wle2, Wln1, Wln2,
                                     nodes, edges,
                                     pan1, pan2, pae1, pae2, ple1, ple2, pln1, pln2,
                                     nodesb, edgesb, ijt);
    k_agg<<<2015, 512, 0, stream>>>(nodesb, edgesb, ijt,
                                    pan1, ban1, pan2, ban2,
                                    pae1, bae1, pae2, bae2, hn, he);
    k_fin<<<64 + 2015, 192, 0, stream>>>(hn, he, nodesb, edgesb, ijt,
                                         pln1, bln1, pln2, bln2, out_nodes,
                                         ple1, ble1, ple2, ble2, out_edges);

    (void)in_sizes; (void)n_in; (void)out_size; (void)ws_size;
}

// Round 13
// 178.906 us; speedup vs baseline: 1.4171x; 1.4171x over previous
//
#include <hip/hip_runtime.h>
#include <cstdint>

#define NN    1024
#define MM    32
#define NEDGE 32240
#define MROWS 64480   // 2*NEDGE
#define PX    168     // X tile pitch (ushorts)
#define PST   392     // unified stage pitch: 256 (H1n) + 128 (H1e) + 8 pad

typedef unsigned short ushort_t;

typedef __bf16 bf16x8 __attribute__((ext_vector_type(8)));
typedef float  floatx4 __attribute__((ext_vector_type(4)));

__device__ __forceinline__ float b2f(ushort_t u) {
    union { unsigned int i; float f; } v; v.i = ((unsigned int)u) << 16; return v.f;
}
__device__ __forceinline__ ushort_t f2b(float f) {
    unsigned int u = __builtin_bit_cast(unsigned int, f);
    u = (u + 0x7FFFu + ((u >> 16) & 1u)) >> 16;
    return (ushort_t)u;
}
// K(i): number of edges before node i
__device__ __forceinline__ int edge_base(int i) {
    return (i <= MM) ? ((i * (i - 1)) >> 1) : (496 + (i - MM) * MM);
}
// edge id e -> (dest i, src j)   [validated round 3]
__device__ __forceinline__ void edge_ij(int e, int& i, int& j) {
    if (e < 496) {
        i = (int)((1.0f + sqrtf(8.0f * (float)e + 1.0f)) * 0.5f);
        while (((i * (i - 1)) >> 1) > e) --i;
        while (((i * (i + 1)) >> 1) <= e) ++i;
        j = e - ((i * (i - 1)) >> 1);
    } else {
        int q = e - 496;
        i = MM + (q >> 5);
        j = i - MM + (q & 31);
    }
}

// ---------------- pack: weight transpose + nodes/edges bf16 + ij table (R11, proven) ----------------
__global__ __launch_bounds__(256) void k_pack(
        const float* an1, const float* an2, const float* ae1, const float* ae2,
        const float* le1, const float* le2, const float* ln1, const float* ln2,
        const float* nodes, const float* edges,
        ushort_t* pan1, ushort_t* pan2, ushort_t* pae1, ushort_t* pae2,
        ushort_t* ple1, ushort_t* ple2, ushort_t* pln1, ushort_t* pln2,
        ushort_t* nodesb, ushort_t* edgesb, int2* ijt) {
    __shared__ float tile[32][33];
    const int bid = blockIdx.x;
    const int tid = threadIdx.x;
    if (bid < 152) {
        const float* s; ushort_t* d; int K, N, t;
        if (bid < 40)       { s = an1; d = pan1; K = 160; N = 256; t = bid;       }
        else if (bid < 72)  { s = an2; d = pan2; K = 256; N = 128; t = bid - 40;  }
        else if (bid < 84)  { s = ae1; d = pae1; K = 96;  N = 128; t = bid - 72;  }
        else if (bid < 92)  { s = ae2; d = pae2; K = 128; N = 64;  t = bid - 84;  }
        else if (bid < 101) { s = le1; d = ple1; K = 96;  N = 96;  t = bid - 92;  }
        else if (bid < 104) { s = le2; d = ple2; K = 96;  N = 32;  t = bid - 101; }
        else if (bid < 140) { s = ln1; d = pln1; K = 192; N = 192; t = bid - 104; }
        else                { s = ln2; d = pln2; K = 192; N = 64;  t = bid - 140; }
        int ntn = N >> 5;
        int tk = t / ntn, tn = t - tk * ntn;
        int k0 = tk * 32, n0 = tn * 32;
        int tx = tid & 31, ty = tid >> 5;
#pragma unroll
        for (int m = 0; m < 4; ++m)
            tile[ty + m * 8][tx] = s[(size_t)(k0 + ty + m * 8) * N + n0 + tx];
        __syncthreads();
#pragma unroll
        for (int m = 0; m < 4; ++m)
            d[(size_t)(n0 + ty + m * 8) * K + k0 + tx] = f2b(tile[tx][ty + m * 8]);
    } else if (bid < 280) {
        int i4 = (bid - 152) * 256 + tid;
        float4 v = ((const float4*)nodes)[i4];
        uint2 o;
        o.x = (unsigned)f2b(v.x) | ((unsigned)f2b(v.y) << 16);
        o.y = (unsigned)f2b(v.z) | ((unsigned)f2b(v.w) << 16);
        ((uint2*)nodesb)[i4] = o;
    } else if (bid < 2296) {
        int i4 = (bid - 280) * 256 + tid;
        if (i4 < 515840) {
            float4 v = ((const float4*)edges)[i4];
            uint2 o;
            o.x = (unsigned)f2b(v.x) | ((unsigned)f2b(v.y) << 16);
            o.y = (unsigned)f2b(v.z) | ((unsigned)f2b(v.w) << 16);
            ((uint2*)edgesb)[i4] = o;
        }
    } else {
        int e = (bid - 2296) * 256 + tid;
        if (e < NEDGE) { int i, j; edge_ij(e, i, j); ijt[e] = make_int2(i, j); }
    }
}

// ---------------- agg: R11 body, 2 tiles per block (B-fragments amortized) ----------------
__global__ __launch_bounds__(512, 2) void k_agg(
        const ushort_t* __restrict__ nodesb, const ushort_t* __restrict__ edgesb,
        const int2* __restrict__ ijt,
        const ushort_t* __restrict__ pan1, const float* __restrict__ ban1,
        const ushort_t* __restrict__ pan2, const float* __restrict__ ban2,
        const ushort_t* __restrict__ pae1, const float* __restrict__ bae1,
        const ushort_t* __restrict__ pae2, const float* __restrict__ bae2,
        ushort_t* __restrict__ hn, ushort_t* __restrict__ he) {
    __shared__ alignas(16) ushort_t X[32 * PX];     // X tile; reused as hn-stage (pitch 136)
    __shared__ alignas(16) ushort_t H[32 * PST];    // H1 tile; reused as he-stage (pitch 72)
    const int tid = threadIdx.x;
    const int w = tid >> 6, l = tid & 63, lrow = l & 15, lq = l >> 4;
    floatx4 zero = {0.f, 0.f, 0.f, 0.f};

    // B fragments for both stages, loaded once, reused across both tiles
    bf16x8 B0[5], B1[5], B2[3];
#pragma unroll
    for (int kt = 0; kt < 5; ++kt) {
        B0[kt] = *(const bf16x8*)(pan1 + (size_t)(16 * w + lrow) * 160 + kt * 32 + lq * 8);
        B1[kt] = *(const bf16x8*)(pan1 + (size_t)(16 * (w + 8) + lrow) * 160 + kt * 32 + lq * 8);
    }
#pragma unroll
    for (int kt = 0; kt < 3; ++kt)
        B2[kt] = *(const bf16x8*)(pae1 + (size_t)(16 * w + lrow) * 96 + kt * 32 + lq * 8);
    float c0 = ban1[16 * w + lrow];
    float c1 = ban1[16 * (w + 8) + lrow];
    float c2 = bae1[16 * w + lrow];
    bf16x8 D0[8], D1[8], E[4];
    float d0 = 0.f, d1 = 0.f, d2 = 0.f;
    if (w < 4) {
#pragma unroll
        for (int kt = 0; kt < 8; ++kt) {
            D0[kt] = *(const bf16x8*)(pan2 + (size_t)(16 * w + lrow) * 256 + kt * 32 + lq * 8);
            D1[kt] = *(const bf16x8*)(pan2 + (size_t)(16 * (w + 4) + lrow) * 256 + kt * 32 + lq * 8);
        }
        d0 = ban2[16 * w + lrow];
        d1 = ban2[16 * (w + 4) + lrow];
    } else {
        int u = w - 4;
#pragma unroll
        for (int kt = 0; kt < 4; ++kt)
            E[kt] = *(const bf16x8*)(pae2 + (size_t)(16 * u + lrow) * 128 + kt * 32 + lq * 8);
        d2 = bae2[16 * u + lrow];
    }

    for (int it = 0; it < 2; ++it) {
        int mt = blockIdx.x + it * 1008;
        if (mt >= 2015) break;
        if (it) __syncthreads();                     // protect LDS reuse across iterations

        // gather: wave w rows w*4..w*4+3, coalesced segments
#pragma unroll
        for (int k = 0; k < 4; ++k) {
            int rr = w * 4 + k;
            int r = mt * 32 + rr;
            int off = (r >= NEDGE) ? 1 : 0;
            int2 ij = ijt[r - off * NEDGE];
            int bN = off * NN;
            unsigned* xr = (unsigned*)(X + rr * PX);
            const unsigned* nj = (const unsigned*)(nodesb + (size_t)(bN + ij.y) * 64);
            const unsigned* ni = (const unsigned*)(nodesb + (size_t)(bN + ij.x) * 64);
            const unsigned* eb = (const unsigned*)(edgesb + (size_t)r * 32);
            if (l < 32) { xr[l] = nj[l]; xr[48 + l] = ni[l]; }
            else        xr[l] = eb[l - 32];
        }
        __syncthreads();

        // stage 1
#pragma unroll
        for (int s = 0; s < 2; ++s) {
            bf16x8 A[5];
#pragma unroll
            for (int kt = 0; kt < 5; ++kt)
                A[kt] = *(const bf16x8*)&X[(s * 16 + lrow) * PX + kt * 32 + lq * 8];
            floatx4 a0 = zero, a1 = zero, a2 = zero;
#pragma unroll
            for (int kt = 0; kt < 5; ++kt) {
                a0 = __builtin_amdgcn_mfma_f32_16x16x32_bf16(A[kt], B0[kt], a0, 0, 0, 0);
                a1 = __builtin_amdgcn_mfma_f32_16x16x32_bf16(A[kt], B1[kt], a1, 0, 0, 0);
            }
#pragma unroll
            for (int kt = 0; kt < 3; ++kt)
                a2 = __builtin_amdgcn_mfma_f32_16x16x32_bf16(A[kt], B2[kt], a2, 0, 0, 0);
#pragma unroll
            for (int r_ = 0; r_ < 4; ++r_) {
                int row = (s * 16 + lq * 4 + r_) * PST;
                H[row + 16 * w + lrow]       = f2b(fmaxf(a0[r_] + c0, 0.f));
                H[row + 128 + 16 * w + lrow] = f2b(fmaxf(a1[r_] + c1, 0.f));
                H[row + 256 + 16 * w + lrow] = f2b(fmaxf(a2[r_] + c2, 0.f));
            }
        }
        __syncthreads();

        // stage 2
        floatx4 o0[2], o1[2];
        if (w < 4) {
#pragma unroll
            for (int s = 0; s < 2; ++s) {
                floatx4 a0 = zero, a1 = zero;
#pragma unroll
                for (int kt = 0; kt < 8; ++kt) {
                    bf16x8 a = *(const bf16x8*)&H[(s * 16 + lrow) * PST + kt * 32 + lq * 8];
                    a0 = __builtin_amdgcn_mfma_f32_16x16x32_bf16(a, D0[kt], a0, 0, 0, 0);
                    a1 = __builtin_amdgcn_mfma_f32_16x16x32_bf16(a, D1[kt], a1, 0, 0, 0);
                }
#pragma unroll
                for (int r_ = 0; r_ < 4; ++r_) { o0[s][r_] = a0[r_] + d0; o1[s][r_] = a1[r_] + d1; }
            }
        } else {
#pragma unroll
            for (int s = 0; s < 2; ++s) {
                floatx4 a2 = zero;
#pragma unroll
                for (int kt = 0; kt < 4; ++kt) {
                    bf16x8 a = *(const bf16x8*)&H[(s * 16 + lrow) * PST + 256 + kt * 32 + lq * 8];
                    a2 = __builtin_amdgcn_mfma_f32_16x16x32_bf16(a, E[kt], a2, 0, 0, 0);
                }
#pragma unroll
                for (int r_ = 0; r_ < 4; ++r_) o0[s][r_] = a2[r_] + d2;
            }
        }
        __syncthreads();

        // stage fragments -> LDS, then dense coalesced stores
        ushort_t* S = X;
        ushort_t* T = H;
        if (w < 4) {
#pragma unroll
            for (int s = 0; s < 2; ++s)
#pragma unroll
                for (int r_ = 0; r_ < 4; ++r_) {
                    int row = (s * 16 + lq * 4 + r_) * 136;
                    S[row + 16 * w + lrow]      = f2b(fmaxf(o0[s][r_], 0.f));
                    S[row + 64 + 16 * w + lrow] = f2b(fmaxf(o1[s][r_], 0.f));
                }
        } else {
            int u = w - 4;
#pragma unroll
            for (int s = 0; s < 2; ++s)
#pragma unroll
                for (int r_ = 0; r_ < 4; ++r_)
                    T[(s * 16 + lq * 4 + r_) * 72 + 16 * u + lrow] = f2b(fmaxf(o0[s][r_], 0.f));
        }
        __syncthreads();
        {
            int row = tid >> 4, c = tid & 15;
            ((uint4*)(hn + (size_t)(mt * 32 + row) * 128))[c] = *(const uint4*)&S[row * 136 + c * 8];
            if (tid < 256) {
                int row2 = tid >> 3, c2 = tid & 7;
                ((uint4*)(he + (size_t)(mt * 32 + row2) * 64))[c2] = *(const uint4*)&T[row2 * 72 + c2 * 8];
            }
        }
    }
}

// ---------------- midn: pn = window-parallel mean(hn), 2048 blocks (R11-parallel, proven) ----------------
__global__ __launch_bounds__(256) void k_midn(
        const ushort_t* __restrict__ hn, ushort_t* __restrict__ pn) {
    const int tid = threadIdx.x;
    int ri = blockIdx.x;
    int b = ri >> 10, i = ri & 1023;
    int t = min(i, MM);
    int base = b * NEDGE + edge_base(i);
    int c = tid & 63, g = tid >> 6;
    float s0 = 0.f, s1 = 0.f;
    for (int p = g; p < t; p += 4) {
        unsigned u = ((const unsigned*)(hn + (size_t)(base + p) * 128))[c];
        s0 += b2f((ushort_t)(u & 0xffff));
        s1 += b2f((ushort_t)(u >> 16));
    }
    __shared__ float red[4][128];
    red[g][c * 2] = s0; red[g][c * 2 + 1] = s1;
    __syncthreads();
    if (tid < 64) {
        float inv = 1.0f / (float)max(t, 1);
        float a0 = (red[0][tid * 2] + red[1][tid * 2] + red[2][tid * 2] + red[3][tid * 2]) * inv;
        float a1 = (red[0][tid * 2 + 1] + red[1][tid * 2 + 1] + red[2][tid * 2 + 1] + red[3][tid * 2 + 1]) * inv;
        ((unsigned*)(pn + (size_t)ri * 128))[tid] = (unsigned)f2b(a0) | ((unsigned)f2b(a1) << 16);
    }
}

// ---------------- fin: node MLP (R11, from pn) | edge fused prefix + le12 (R12, verified) ----------------
__global__ __launch_bounds__(192) void k_fin(
        const ushort_t* __restrict__ pn, const ushort_t* __restrict__ nodesb,
        const ushort_t* __restrict__ he, const ushort_t* __restrict__ edgesb,
        const int2* __restrict__ ijt,
        const ushort_t* __restrict__ pln1, const float* __restrict__ bln1,
        const ushort_t* __restrict__ pln2, const float* __restrict__ bln2,
        float* __restrict__ out_nodes,
        const ushort_t* __restrict__ ple1, const float* __restrict__ ble1,
        const ushort_t* __restrict__ ple2, const float* __restrict__ ble2,
        float* __restrict__ out_edges) {
    __shared__ alignas(16) ushort_t LA[32 * 200];
    __shared__ alignas(16) ushort_t LB[32 * 200];   // edge path: first 63*64 aliased as he-window
    __shared__ int pmeta[32];
    const int tid = threadIdx.x;
    const int w = tid >> 6, l = tid & 63, lrow = l & 15, lq = l >> 4;
    floatx4 zero = {0.f, 0.f, 0.f, 0.f};

    if (blockIdx.x < 64) {
        int tile = blockIdx.x;
        for (int u = tid; u < 768; u += 192) {        // 32 rows x 24 uint4 chunks
            int row = u / 24, c = u - row * 24;
            int r = tile * 32 + row;
            const uint4* src = (c < 16) ? ((const uint4*)(pn + (size_t)r * 128) + c)
                                        : ((const uint4*)(nodesb + (size_t)r * 64) + (c - 16));
            *(uint4*)&LA[row * 200 + c * 8] = *src;
        }
        bf16x8 f1[6][4]; float v1[4];
#pragma unroll
        for (int kt = 0; kt < 6; ++kt)
#pragma unroll
            for (int nt = 0; nt < 4; ++nt)
                f1[kt][nt] = *(const bf16x8*)(pln1 + (size_t)(w * 64 + nt * 16 + lrow) * 192 + kt * 32 + lq * 8);
#pragma unroll
        for (int nt = 0; nt < 4; ++nt) v1[nt] = bln1[w * 64 + nt * 16 + lrow];
        __syncthreads();

        floatx4 acc[2][4];
#pragma unroll
        for (int s = 0; s < 2; ++s)
#pragma unroll
            for (int nt = 0; nt < 4; ++nt) acc[s][nt] = zero;
#pragma unroll
        for (int s = 0; s < 2; ++s)
#pragma unroll
            for (int kt = 0; kt < 6; ++kt) {
                bf16x8 a = *(const bf16x8*)&LA[(s * 16 + lrow) * 200 + kt * 32 + lq * 8];
#pragma unroll
                for (int nt = 0; nt < 4; ++nt)
                    acc[s][nt] = __builtin_amdgcn_mfma_f32_16x16x32_bf16(a, f1[kt][nt], acc[s][nt], 0, 0, 0);
            }
#pragma unroll
        for (int s = 0; s < 2; ++s)
#pragma unroll
            for (int nt = 0; nt < 4; ++nt) {
                int col = w * 64 + nt * 16 + lrow;
#pragma unroll
                for (int r_ = 0; r_ < 4; ++r_)
                    LB[(s * 16 + lq * 4 + r_) * 200 + col] = f2b(fmaxf(acc[s][nt][r_] + v1[nt], 0.f));
            }
        bf16x8 f2[6][2]; float v2[2] = {0.f, 0.f};
        if (w < 2) {
#pragma unroll
            for (int kt = 0; kt < 6; ++kt)
#pragma unroll
                for (int nt = 0; nt < 2; ++nt)
                    f2[kt][nt] = *(const bf16x8*)(pln2 + (size_t)(w * 32 + nt * 16 + lrow) * 192 + kt * 32 + lq * 8);
#pragma unroll
            for (int nt = 0; nt < 2; ++nt) v2[nt] = bln2[w * 32 + nt * 16 + lrow];
        }
        __syncthreads();
        if (w < 2) {
            floatx4 a2[2][2];
#pragma unroll
            for (int s = 0; s < 2; ++s) { a2[s][0] = zero; a2[s][1] = zero; }
#pragma unroll
            for (int s = 0; s < 2; ++s)
#pragma unroll
                for (int kt = 0; kt < 6; ++kt) {
                    bf16x8 a = *(const bf16x8*)&LB[(s * 16 + lrow) * 200 + kt * 32 + lq * 8];
#pragma unroll
                    for (int nt = 0; nt < 2; ++nt)
                        a2[s][nt] = __builtin_amdgcn_mfma_f32_16x16x32_bf16(a, f2[kt][nt], a2[s][nt], 0, 0, 0);
                }
#pragma unroll
            for (int s = 0; s < 2; ++s)
#pragma unroll
                for (int nt = 0; nt < 2; ++nt) {
                    int col = w * 32 + nt * 16 + lrow;
#pragma unroll
                    for (int r_ = 0; r_ < 4; ++r_)
                        out_nodes[(size_t)(tile * 32 + s * 16 + lq * 4 + r_) * 64 + col] =
                            fmaxf(a2[s][nt][r_] + v2[nt], 0.f);
                }
        }
    } else {
        // ---- edge path: fused prefix (from he span) + le12 (verified R12) ----
        int mt = blockIdx.x - 64;
        int r0 = mt * 32;
        int lo = max(r0 - 31, 0);
        int nrows = r0 + 32 - lo;                   // <= 63
        ushort_t* HW = LB;                          // he window [nrows][64]
        for (int u = tid; u < nrows * 8; u += 192)
            ((uint4*)HW)[u] = ((const uint4*)(he + (size_t)lo * 64))[u];
        if (tid < 32) {
            int r = r0 + tid;
            int off = (r >= NEDGE) ? 1 : 0;
            int e = r - off * NEDGE;
            pmeta[tid] = e - edge_base(ijt[e].x);
        }
        for (int u = tid; u < 128; u += 192) {
            int row = u >> 2, c = u & 3;
            *(uint4*)&LA[row * 104 + 64 + c * 8] = ((const uint4*)(edgesb + (size_t)(r0 + row) * 32))[c];
        }
        bf16x8 fb1[3][2]; float v1[2];
#pragma unroll
        for (int kt = 0; kt < 3; ++kt)
#pragma unroll
            for (int nt = 0; nt < 2; ++nt)
                fb1[kt][nt] = *(const bf16x8*)(ple1 + (size_t)(w * 32 + nt * 16 + lrow) * 96 + kt * 32 + lq * 8);
#pragma unroll
        for (int nt = 0; nt < 2; ++nt) v1[nt] = ble1[w * 32 + nt * 16 + lrow];
        bf16x8 fb2[3]; float v2 = 0.f;
        if (w < 2) {
#pragma unroll
            for (int kt = 0; kt < 3; ++kt)
                fb2[kt] = *(const bf16x8*)(ple2 + (size_t)(w * 16 + lrow) * 96 + kt * 32 + lq * 8);
            v2 = ble2[w * 16 + lrow];
        }
        __syncthreads();

        if (tid < 64) {
            int c = tid;
            int p0 = pmeta[0];
            float run = 0.f;
            for (int q = r0 - p0 - lo; q < r0 - lo; ++q) run += b2f(HW[q * 64 + c]);
            for (int k = 0; k < 32; ++k) {
                int p = pmeta[k];
                float v;
                if (p == 0) { run = 0.f; v = 0.f; }
                else v = run / (float)p;
                LA[k * 104 + c] = f2b(v);
                run += b2f(HW[(r0 + k - lo) * 64 + c]);
            }
        }
        __syncthreads();

        floatx4 acc[2][2];
#pragma unroll
        for (int s = 0; s < 2; ++s) { acc[s][0] = zero; acc[s][1] = zero; }
#pragma unroll
        for (int s = 0; s < 2; ++s)
#pragma unroll
            for (int kt = 0; kt < 3; ++kt) {
                bf16x8 a = *(const bf16x8*)&LA[(s * 16 + lrow) * 104 + kt * 32 + lq * 8];
#pragma unroll
                for (int nt = 0; nt < 2; ++nt)
                    acc[s][nt] = __builtin_amdgcn_mfma_f32_16x16x32_bf16(a, fb1[kt][nt], acc[s][nt], 0, 0, 0);
            }
        __syncthreads();                             // HW reads done; LB reusable
#pragma unroll
        for (int s = 0; s < 2; ++s)
#pragma unroll
            for (int nt = 0; nt < 2; ++nt) {
                int col = w * 32 + nt * 16 + lrow;
#pragma unroll
                for (int r_ = 0; r_ < 4; ++r_)
                    LB[(s * 16 + lq * 4 + r_) * 104 + col] = f2b(fmaxf(acc[s][nt][r_] + v1[nt], 0.f));
            }
        __syncthreads();
        if (w < 2) {
            floatx4 a2[2] = {zero, zero};
#pragma unroll
            for (int s = 0; s < 2; ++s)
#pragma unroll
                for (int kt = 0; kt < 3; ++kt) {
                    bf16x8 a = *(const bf16x8*)&LB[(s * 16 + lrow) * 104 + kt * 32 + lq * 8];
                    a2[s] = __builtin_amdgcn_mfma_f32_16x16x32_bf16(a, fb2[kt], a2[s], 0, 0, 0);
                }
#pragma unroll
            for (int s = 0; s < 2; ++s) {
                int col = w * 16 + lrow;
#pragma unroll
                for (int r_ = 0; r_ < 4; ++r_)
                    out_edges[(size_t)(mt * 32 + s * 16 + lq * 4 + r_) * 32 + col] = fmaxf(a2[s][r_] + v2, 0.f);
            }
        }
    }
}

extern "C" void kernel_launch(void* const* d_in, const int* in_sizes, int n_in,
                              void* d_out, int out_size, void* d_ws, size_t ws_size,
                              hipStream_t stream) {
    const float* nodes = (const float*)d_in[0];
    const float* edges = (const float*)d_in[1];
    const float* Wan1 = (const float*)d_in[2];  const float* ban1 = (const float*)d_in[3];
    const float* Wan2 = (const float*)d_in[4];  const float* ban2 = (const float*)d_in[5];
    const float* Wln1 = (const float*)d_in[6];  const float* bln1 = (const float*)d_in[7];
    const float* Wln2 = (const float*)d_in[8];  const float* bln2 = (const float*)d_in[9];
    const float* Wae1 = (const float*)d_in[10]; const float* bae1 = (const float*)d_in[11];
    const float* Wae2 = (const float*)d_in[12]; const float* bae2 = (const float*)d_in[13];
    const float* Wle1 = (const float*)d_in[14]; const float* ble1 = (const float*)d_in[15];
    const float* Wle2 = (const float*)d_in[16]; const float* ble2 = (const float*)d_in[17];

    char* ws = (char*)d_ws;
    size_t o = 0;
    auto alloc = [&](size_t bytes) -> void* {
        void* r = ws + o;
        o += (bytes + 255) & ~(size_t)255;
        return r;
    };
    ushort_t* hn     = (ushort_t*)alloc((size_t)MROWS * 128 * 2);
    ushort_t* he     = (ushort_t*)alloc((size_t)MROWS * 64 * 2);
    ushort_t* pn     = (ushort_t*)alloc((size_t)2048 * 128 * 2);
    ushort_t* nodesb = (ushort_t*)alloc((size_t)2 * NN * 64 * 2);
    ushort_t* edgesb = (ushort_t*)alloc((size_t)MROWS * 32 * 2);
    int2*     ijt    = (int2*)alloc((size_t)NEDGE * 8);
    ushort_t* pan1 = (ushort_t*)alloc(160 * 256 * 2);
    ushort_t* pan2 = (ushort_t*)alloc(256 * 128 * 2);
    ushort_t* pae1 = (ushort_t*)alloc(96 * 128 * 2);
    ushort_t* pae2 = (ushort_t*)alloc(128 * 64 * 2);
    ushort_t* ple1 = (ushort_t*)alloc(96 * 96 * 2);
    ushort_t* ple2 = (ushort_t*)alloc(96 * 32 * 2);
    ushort_t* pln1 = (ushort_t*)alloc(192 * 192 * 2);
    ushort_t* pln2 = (ushort_t*)alloc(192 * 64 * 2);

    float* out_nodes = (float*)d_out;
    float* out_edges = (float*)d_out + 2 * NN * 64;

    k_pack<<<2422, 256, 0, stream>>>(Wan1, Wan2, Wae1, Wae2, Wle1, Wle2, Wln1, Wln2,
                                     nodes, edges,
                                     pan1, pan2, pae1, pae2, ple1, ple2, pln1, pln2,
                                     nodesb, edgesb, ijt);
    k_agg<<<1008, 512, 0, stream>>>(nodesb, edgesb, ijt,
                                    pan1, ban1, pan2, ban2,
                                    pae1, bae1, pae2, bae2, hn, he);
    k_midn<<<2048, 256, 0, stream>>>(hn, pn);
    k_fin<<<64 + 2015, 192, 0, stream>>>(pn, nodesb, he, edgesb, ijt,
                                         pln1, bln1, pln2, bln2, out_nodes,
                                         ple1, ble1, ple2, ble2, out_edges);

    (void)in_sizes; (void)n_in; (void)out_size; (void)ws_size;
}

// Round 14
// 168.577 us; speedup vs baseline: 1.5040x; 1.0613x over previous
//
#include <hip/hip_runtime.h>
#include <cstdint>

#define NN    1024
#define MM    32
#define NEDGE 32240
#define MROWS 64480   // 2*NEDGE
#define PX    168     // X tile pitch (ushorts)
#define PST   392     // unified stage pitch: 256 (H1n) + 128 (H1e) + 8 pad

typedef unsigned short ushort_t;

typedef __bf16 bf16x8 __attribute__((ext_vector_type(8)));
typedef float  floatx4 __attribute__((ext_vector_type(4)));

__device__ __forceinline__ float b2f(ushort_t u) {
    union { unsigned int i; float f; } v; v.i = ((unsigned int)u) << 16; return v.f;
}
__device__ __forceinline__ ushort_t f2b(float f) {
    unsigned int u = __builtin_bit_cast(unsigned int, f);
    u = (u + 0x7FFFu + ((u >> 16) & 1u)) >> 16;
    return (ushort_t)u;
}
// K(i): number of edges before node i
__device__ __forceinline__ int edge_base(int i) {
    return (i <= MM) ? ((i * (i - 1)) >> 1) : (496 + (i - MM) * MM);
}
// edge id e -> (dest i, src j)   [validated round 3]
__device__ __forceinline__ void edge_ij(int e, int& i, int& j) {
    if (e < 496) {
        i = (int)((1.0f + sqrtf(8.0f * (float)e + 1.0f)) * 0.5f);
        while (((i * (i - 1)) >> 1) > e) --i;
        while (((i * (i + 1)) >> 1) <= e) ++i;
        j = e - ((i * (i - 1)) >> 1);
    } else {
        int q = e - 496;
        i = MM + (q >> 5);
        j = i - MM + (q & 31);
    }
}

// ---------------- pack: weight transpose + nodes/edges bf16 + ij table + pnf zero ----------------
__global__ __launch_bounds__(256) void k_pack(
        const float* an1, const float* an2, const float* ae1, const float* ae2,
        const float* le1, const float* le2, const float* ln1, const float* ln2,
        const float* nodes, const float* edges,
        ushort_t* pan1, ushort_t* pan2, ushort_t* pae1, ushort_t* pae2,
        ushort_t* ple1, ushort_t* ple2, ushort_t* pln1, ushort_t* pln2,
        ushort_t* nodesb, ushort_t* edgesb, int2* ijt, float* pnf) {
    __shared__ float tile[32][33];
    const int bid = blockIdx.x;
    const int tid = threadIdx.x;
    if (bid < 152) {
        const float* s; ushort_t* d; int K, N, t;
        if (bid < 40)       { s = an1; d = pan1; K = 160; N = 256; t = bid;       }
        else if (bid < 72)  { s = an2; d = pan2; K = 256; N = 128; t = bid - 40;  }
        else if (bid < 84)  { s = ae1; d = pae1; K = 96;  N = 128; t = bid - 72;  }
        else if (bid < 92)  { s = ae2; d = pae2; K = 128; N = 64;  t = bid - 84;  }
        else if (bid < 101) { s = le1; d = ple1; K = 96;  N = 96;  t = bid - 92;  }
        else if (bid < 104) { s = le2; d = ple2; K = 96;  N = 32;  t = bid - 101; }
        else if (bid < 140) { s = ln1; d = pln1; K = 192; N = 192; t = bid - 104; }
        else                { s = ln2; d = pln2; K = 192; N = 64;  t = bid - 140; }
        int ntn = N >> 5;
        int tk = t / ntn, tn = t - tk * ntn;
        int k0 = tk * 32, n0 = tn * 32;
        int tx = tid & 31, ty = tid >> 5;
#pragma unroll
        for (int m = 0; m < 4; ++m)
            tile[ty + m * 8][tx] = s[(size_t)(k0 + ty + m * 8) * N + n0 + tx];
        __syncthreads();
#pragma unroll
        for (int m = 0; m < 4; ++m)
            d[(size_t)(n0 + ty + m * 8) * K + k0 + tx] = f2b(tile[tx][ty + m * 8]);
    } else if (bid < 280) {
        int i4 = (bid - 152) * 256 + tid;
        float4 v = ((const float4*)nodes)[i4];
        uint2 o;
        o.x = (unsigned)f2b(v.x) | ((unsigned)f2b(v.y) << 16);
        o.y = (unsigned)f2b(v.z) | ((unsigned)f2b(v.w) << 16);
        ((uint2*)nodesb)[i4] = o;
    } else if (bid < 2296) {
        int i4 = (bid - 280) * 256 + tid;
        if (i4 < 515840) {
            float4 v = ((const float4*)edges)[i4];
            uint2 o;
            o.x = (unsigned)f2b(v.x) | ((unsigned)f2b(v.y) << 16);
            o.y = (unsigned)f2b(v.z) | ((unsigned)f2b(v.w) << 16);
            ((uint2*)edgesb)[i4] = o;
        }
    } else if (bid < 2422) {
        int e = (bid - 2296) * 256 + tid;
        if (e < NEDGE) { int i, j; edge_ij(e, i, j); ijt[e] = make_int2(i, j); }
    } else {
        // zero pnf: 2048*128 floats = 65536 float4
        int i4 = (bid - 2422) * 256 + tid;
        float4 z = {0.f, 0.f, 0.f, 0.f};
        ((float4*)pnf)[i4] = z;
    }
}

// ---------------- agg: R11 one-tile body + segmented pn atomics ----------------
__global__ __launch_bounds__(512, 2) void k_agg(
        const ushort_t* __restrict__ nodesb, const ushort_t* __restrict__ edgesb,
        const int2* __restrict__ ijt,
        const ushort_t* __restrict__ pan1, const float* __restrict__ ban1,
        const ushort_t* __restrict__ pan2, const float* __restrict__ ban2,
        const ushort_t* __restrict__ pae1, const float* __restrict__ bae1,
        const ushort_t* __restrict__ pae2, const float* __restrict__ bae2,
        ushort_t* __restrict__ hn, ushort_t* __restrict__ he,
        float* __restrict__ pnf) {
    __shared__ alignas(16) ushort_t X[32 * PX];     // X tile; reused as hn-stage (pitch 136)
    __shared__ alignas(16) ushort_t H[32 * PST];    // H1 tile; reused as he-stage (pitch 72)
    __shared__ int ndxs[32];                        // per-row dest node (global index 0..2047)
    const int tid = threadIdx.x;
    const int w = tid >> 6, l = tid & 63, lrow = l & 15, lq = l >> 4;
    const int mt = blockIdx.x;
    floatx4 zero = {0.f, 0.f, 0.f, 0.f};

    bf16x8 B0[5], B1[5], B2[3];
#pragma unroll
    for (int kt = 0; kt < 5; ++kt) {
        B0[kt] = *(const bf16x8*)(pan1 + (size_t)(16 * w + lrow) * 160 + kt * 32 + lq * 8);
        B1[kt] = *(const bf16x8*)(pan1 + (size_t)(16 * (w + 8) + lrow) * 160 + kt * 32 + lq * 8);
    }
#pragma unroll
    for (int kt = 0; kt < 3; ++kt)
        B2[kt] = *(const bf16x8*)(pae1 + (size_t)(16 * w + lrow) * 96 + kt * 32 + lq * 8);
    float c0 = ban1[16 * w + lrow];
    float c1 = ban1[16 * (w + 8) + lrow];
    float c2 = bae1[16 * w + lrow];

#pragma unroll
    for (int k = 0; k < 4; ++k) {
        int rr = w * 4 + k;
        int r = mt * 32 + rr;
        int off = (r >= NEDGE) ? 1 : 0;
        int2 ij = ijt[r - off * NEDGE];
        int bN = off * NN;
        unsigned* xr = (unsigned*)(X + rr * PX);
        const unsigned* nj = (const unsigned*)(nodesb + (size_t)(bN + ij.y) * 64);
        const unsigned* ni = (const unsigned*)(nodesb + (size_t)(bN + ij.x) * 64);
        const unsigned* eb = (const unsigned*)(edgesb + (size_t)r * 32);
        if (l < 32) { xr[l] = nj[l]; xr[48 + l] = ni[l]; }
        else        xr[l] = eb[l - 32];
        if (l == 0) ndxs[rr] = bN + ij.x;
    }
    __syncthreads();

#pragma unroll
    for (int s = 0; s < 2; ++s) {
        bf16x8 A[5];
#pragma unroll
        for (int kt = 0; kt < 5; ++kt)
            A[kt] = *(const bf16x8*)&X[(s * 16 + lrow) * PX + kt * 32 + lq * 8];
        floatx4 a0 = zero, a1 = zero, a2 = zero;
#pragma unroll
        for (int kt = 0; kt < 5; ++kt) {
            a0 = __builtin_amdgcn_mfma_f32_16x16x32_bf16(A[kt], B0[kt], a0, 0, 0, 0);
            a1 = __builtin_amdgcn_mfma_f32_16x16x32_bf16(A[kt], B1[kt], a1, 0, 0, 0);
        }
#pragma unroll
        for (int kt = 0; kt < 3; ++kt)
            a2 = __builtin_amdgcn_mfma_f32_16x16x32_bf16(A[kt], B2[kt], a2, 0, 0, 0);
#pragma unroll
        for (int r_ = 0; r_ < 4; ++r_) {
            int row = (s * 16 + lq * 4 + r_) * PST;
            H[row + 16 * w + lrow]       = f2b(fmaxf(a0[r_] + c0, 0.f));
            H[row + 128 + 16 * w + lrow] = f2b(fmaxf(a1[r_] + c1, 0.f));
            H[row + 256 + 16 * w + lrow] = f2b(fmaxf(a2[r_] + c2, 0.f));
        }
    }
    __syncthreads();

    floatx4 o0[2], o1[2];
    if (w < 4) {
        bf16x8 D0[8], D1[8];
#pragma unroll
        for (int kt = 0; kt < 8; ++kt) {
            D0[kt] = *(const bf16x8*)(pan2 + (size_t)(16 * w + lrow) * 256 + kt * 32 + lq * 8);
            D1[kt] = *(const bf16x8*)(pan2 + (size_t)(16 * (w + 4) + lrow) * 256 + kt * 32 + lq * 8);
        }
        float d0 = ban2[16 * w + lrow];
        float d1 = ban2[16 * (w + 4) + lrow];
#pragma unroll
        for (int s = 0; s < 2; ++s) {
            floatx4 a0 = zero, a1 = zero;
#pragma unroll
            for (int kt = 0; kt < 8; ++kt) {
                bf16x8 a = *(const bf16x8*)&H[(s * 16 + lrow) * PST + kt * 32 + lq * 8];
                a0 = __builtin_amdgcn_mfma_f32_16x16x32_bf16(a, D0[kt], a0, 0, 0, 0);
                a1 = __builtin_amdgcn_mfma_f32_16x16x32_bf16(a, D1[kt], a1, 0, 0, 0);
            }
#pragma unroll
            for (int r_ = 0; r_ < 4; ++r_) { o0[s][r_] = a0[r_] + d0; o1[s][r_] = a1[r_] + d1; }
        }
    } else {
        int u = w - 4;
        bf16x8 E[4];
#pragma unroll
        for (int kt = 0; kt < 4; ++kt)
            E[kt] = *(const bf16x8*)(pae2 + (size_t)(16 * u + lrow) * 128 + kt * 32 + lq * 8);
        float d2 = bae2[16 * u + lrow];
#pragma unroll
        for (int s = 0; s < 2; ++s) {
            floatx4 a2 = zero;
#pragma unroll
            for (int kt = 0; kt < 4; ++kt) {
                bf16x8 a = *(const bf16x8*)&H[(s * 16 + lrow) * PST + 256 + kt * 32 + lq * 8];
                a2 = __builtin_amdgcn_mfma_f32_16x16x32_bf16(a, E[kt], a2, 0, 0, 0);
            }
#pragma unroll
            for (int r_ = 0; r_ < 4; ++r_) o0[s][r_] = a2[r_] + d2;
        }
    }
    __syncthreads();

    ushort_t* S = X;
    ushort_t* T = H;
    if (w < 4) {
#pragma unroll
        for (int s = 0; s < 2; ++s)
#pragma unroll
            for (int r_ = 0; r_ < 4; ++r_) {
                int row = (s * 16 + lq * 4 + r_) * 136;
                S[row + 16 * w + lrow]      = f2b(fmaxf(o0[s][r_], 0.f));
                S[row + 64 + 16 * w + lrow] = f2b(fmaxf(o1[s][r_], 0.f));
            }
    } else {
        int u = w - 4;
#pragma unroll
        for (int s = 0; s < 2; ++s)
#pragma unroll
            for (int r_ = 0; r_ < 4; ++r_)
                T[(s * 16 + lq * 4 + r_) * 72 + 16 * u + lrow] = f2b(fmaxf(o0[s][r_], 0.f));
    }
    __syncthreads();

    {
        int row = tid >> 4, c = tid & 15;
        ((uint4*)(hn + (size_t)(mt * 32 + row) * 128))[c] = *(const uint4*)&S[row * 136 + c * 8];
        if (tid < 256) {
            int row2 = tid >> 3, c2 = tid & 7;
            ((uint4*)(he + (size_t)(mt * 32 + row2) * 64))[c2] = *(const uint4*)&T[row2 * 72 + c2 * 8];
        }
    }

    // segmented pn accumulation: thread c (<128) walks 32 rows of the bf16 hn tile in S,
    // emits one fp32 atomicAdd per (dest-node, col) run. S/ndxs stable (no writes after barrier).
    if (tid < 128) {
        float acc = 0.f;
        int cur = ndxs[0];
        for (int row = 0; row < 32; ++row) {
            int nd = ndxs[row];
            if (nd != cur) {
                atomicAdd(&pnf[(size_t)cur * 128 + tid], acc);
                acc = 0.f; cur = nd;
            }
            acc += b2f(S[row * 136 + tid]);
        }
        atomicAdd(&pnf[(size_t)cur * 128 + tid], acc);
    }
}

// ---------------- fin: node MLP (pnf-scaled) | edge fused prefix + le12 (R12/R13, verified) ----------------
__global__ __launch_bounds__(192) void k_fin(
        const float* __restrict__ pnf, const ushort_t* __restrict__ nodesb,
        const ushort_t* __restrict__ he, const ushort_t* __restrict__ edgesb,
        const int2* __restrict__ ijt,
        const ushort_t* __restrict__ pln1, const float* __restrict__ bln1,
        const ushort_t* __restrict__ pln2, const float* __restrict__ bln2,
        float* __restrict__ out_nodes,
        const ushort_t* __restrict__ ple1, const float* __restrict__ ble1,
        const ushort_t* __restrict__ ple2, const float* __restrict__ ble2,
        float* __restrict__ out_edges) {
    __shared__ alignas(16) ushort_t LA[32 * 200];
    __shared__ alignas(16) ushort_t LB[32 * 200];   // edge path: first 63*64 aliased as he-window
    __shared__ int pmeta[32];
    const int tid = threadIdx.x;
    const int w = tid >> 6, l = tid & 63, lrow = l & 15, lq = l >> 4;
    floatx4 zero = {0.f, 0.f, 0.f, 0.f};

    if (blockIdx.x < 64) {
        int tile = blockIdx.x;
        // stage [f2b(pnf * 1/t) (128) | nodesb (64)] rows, pitch 200
        for (int u = tid; u < 4096; u += 192) {
            int row = u >> 7, c = u & 127;
            int r = tile * 32 + row;
            int i = r & 1023;
            int t = min(i, MM);
            float inv = 1.0f / (float)max(t, 1);
            LA[row * 200 + c] = f2b(pnf[(size_t)r * 128 + c] * inv);
        }
        for (int u = tid; u < 256; u += 192) {
            int row = u >> 3, c = u & 7;
            *(uint4*)&LA[row * 200 + 128 + c * 8] =
                ((const uint4*)(nodesb + (size_t)(tile * 32 + row) * 64))[c];
        }
        bf16x8 f1[6][4]; float v1[4];
#pragma unroll
        for (int kt = 0; kt < 6; ++kt)
#pragma unroll
            for (int nt = 0; nt < 4; ++nt)
                f1[kt][nt] = *(const bf16x8*)(pln1 + (size_t)(w * 64 + nt * 16 + lrow) * 192 + kt * 32 + lq * 8);
#pragma unroll
        for (int nt = 0; nt < 4; ++nt) v1[nt] = bln1[w * 64 + nt * 16 + lrow];
        __syncthreads();

        floatx4 acc[2][4];
#pragma unroll
        for (int s = 0; s < 2; ++s)
#pragma unroll
            for (int nt = 0; nt < 4; ++nt) acc[s][nt] = zero;
#pragma unroll
        for (int s = 0; s < 2; ++s)
#pragma unroll
            for (int kt = 0; kt < 6; ++kt) {
                bf16x8 a = *(const bf16x8*)&LA[(s * 16 + lrow) * 200 + kt * 32 + lq * 8];
#pragma unroll
                for (int nt = 0; nt < 4; ++nt)
                    acc[s][nt] = __builtin_amdgcn_mfma_f32_16x16x32_bf16(a, f1[kt][nt], acc[s][nt], 0, 0, 0);
            }
#pragma unroll
        for (int s = 0; s < 2; ++s)
#pragma unroll
            for (int nt = 0; nt < 4; ++nt) {
                int col = w * 64 + nt * 16 + lrow;
#pragma unroll
                for (int r_ = 0; r_ < 4; ++r_)
                    LB[(s * 16 + lq * 4 + r_) * 200 + col] = f2b(fmaxf(acc[s][nt][r_] + v1[nt], 0.f));
            }
        bf16x8 f2[6][2]; float v2[2] = {0.f, 0.f};
        if (w < 2) {
#pragma unroll
            for (int kt = 0; kt < 6; ++kt)
#pragma unroll
                for (int nt = 0; nt < 2; ++nt)
                    f2[kt][nt] = *(const bf16x8*)(pln2 + (size_t)(w * 32 + nt * 16 + lrow) * 192 + kt * 32 + lq * 8);
#pragma unroll
            for (int nt = 0; nt < 2; ++nt) v2[nt] = bln2[w * 32 + nt * 16 + lrow];
        }
        __syncthreads();
        if (w < 2) {
            floatx4 a2[2][2];
#pragma unroll
            for (int s = 0; s < 2; ++s) { a2[s][0] = zero; a2[s][1] = zero; }
#pragma unroll
            for (int s = 0; s < 2; ++s)
#pragma unroll
                for (int kt = 0; kt < 6; ++kt) {
                    bf16x8 a = *(const bf16x8*)&LB[(s * 16 + lrow) * 200 + kt * 32 + lq * 8];
#pragma unroll
                    for (int nt = 0; nt < 2; ++nt)
                        a2[s][nt] = __builtin_amdgcn_mfma_f32_16x16x32_bf16(a, f2[kt][nt], a2[s][nt], 0, 0, 0);
                }
#pragma unroll
            for (int s = 0; s < 2; ++s)
#pragma unroll
                for (int nt = 0; nt < 2; ++nt) {
                    int col = w * 32 + nt * 16 + lrow;
#pragma unroll
                    for (int r_ = 0; r_ < 4; ++r_)
                        out_nodes[(size_t)(tile * 32 + s * 16 + lq * 4 + r_) * 64 + col] =
                            fmaxf(a2[s][nt][r_] + v2[nt], 0.f);
                }
        }
    } else {
        // ---- edge path: fused prefix (from he span) + le12 (verified R12/R13) ----
        int mt = blockIdx.x - 64;
        int r0 = mt * 32;
        int lo = max(r0 - 31, 0);
        int nrows = r0 + 32 - lo;                   // <= 63
        ushort_t* HW = LB;                          // he window [nrows][64]
        for (int u = tid; u < nrows * 8; u += 192)
            ((uint4*)HW)[u] = ((const uint4*)(he + (size_t)lo * 64))[u];
        if (tid < 32) {
            int r = r0 + tid;
            int off = (r >= NEDGE) ? 1 : 0;
            int e = r - off * NEDGE;
            pmeta[tid] = e - edge_base(ijt[e].x);
        }
        for (int u = tid; u < 128; u += 192) {
            int row = u >> 2, c = u & 3;
            *(uint4*)&LA[row * 104 + 64 + c * 8] = ((const uint4*)(edgesb + (size_t)(r0 + row) * 32))[c];
        }
        bf16x8 fb1[3][2]; float v1[2];
#pragma unroll
        for (int kt = 0; kt < 3; ++kt)
#pragma unroll
            for (int nt = 0; nt < 2; ++nt)
                fb1[kt][nt] = *(const bf16x8*)(ple1 + (size_t)(w * 32 + nt * 16 + lrow) * 96 + kt * 32 + lq * 8);
#pragma unroll
        for (int nt = 0; nt < 2; ++nt) v1[nt] = ble1[w * 32 + nt * 16 + lrow];
        bf16x8 fb2[3]; float v2 = 0.f;
        if (w < 2) {
#pragma unroll
            for (int kt = 0; kt < 3; ++kt)
                fb2[kt] = *(const bf16x8*)(ple2 + (size_t)(w * 16 + lrow) * 96 + kt * 32 + lq * 8);
            v2 = ble2[w * 16 + lrow];
        }
        __syncthreads();

        if (tid < 64) {
            int c = tid;
            int p0 = pmeta[0];
            float run = 0.f;
            for (int q = r0 - p0 - lo; q < r0 - lo; ++q) run += b2f(HW[q * 64 + c]);
            for (int k = 0; k < 32; ++k) {
                int p = pmeta[k];
                float v;
                if (p == 0) { run = 0.f; v = 0.f; }
                else v = run / (float)p;
                LA[k * 104 + c] = f2b(v);
                run += b2f(HW[(r0 + k - lo) * 64 + c]);
            }
        }
        __syncthreads();

        floatx4 acc[2][2];
#pragma unroll
        for (int s = 0; s < 2; ++s) { acc[s][0] = zero; acc[s][1] = zero; }
#pragma unroll
        for (int s = 0; s < 2; ++s)
#pragma unroll
            for (int kt = 0; kt < 3; ++kt) {
                bf16x8 a = *(const bf16x8*)&LA[(s * 16 + lrow) * 104 + kt * 32 + lq * 8];
#pragma unroll
                for (int nt = 0; nt < 2; ++nt)
                    acc[s][nt] = __builtin_amdgcn_mfma_f32_16x16x32_bf16(a, fb1[kt][nt], acc[s][nt], 0, 0, 0);
            }
        __syncthreads();                             // HW reads done; LB reusable
#pragma unroll
        for (int s = 0; s < 2; ++s)
#pragma unroll
            for (int nt = 0; nt < 2; ++nt) {
                int col = w * 32 + nt * 16 + lrow;
#pragma unroll
                for (int r_ = 0; r_ < 4; ++r_)
                    LB[(s * 16 + lq * 4 + r_) * 104 + col] = f2b(fmaxf(acc[s][nt][r_] + v1[nt], 0.f));
            }
        __syncthreads();
        if (w < 2) {
            floatx4 a2[2] = {zero, zero};
#pragma unroll
            for (int s = 0; s < 2; ++s)
#pragma unroll
                for (int kt = 0; kt < 3; ++kt) {
                    bf16x8 a = *(const bf16x8*)&LB[(s * 16 + lrow) * 104 + kt * 32 + lq * 8];
                    a2[s] = __builtin_amdgcn_mfma_f32_16x16x32_bf16(a, fb2[kt], a2[s], 0, 0, 0);
                }
#pragma unroll
            for (int s = 0; s < 2; ++s) {
                int col = w * 16 + lrow;
#pragma unroll
                for (int r_ = 0; r_ < 4; ++r_)
                    out_edges[(size_t)(mt * 32 + s * 16 + lq * 4 + r_) * 32 + col] = fmaxf(a2[s][r_] + v2, 0.f);
            }
        }
    }
}

extern "C" void kernel_launch(void* const* d_in, const int* in_sizes, int n_in,
                              void* d_out, int out_size, void* d_ws, size_t ws_size,
                              hipStream_t stream) {
    const float* nodes = (const float*)d_in[0];
    const float* edges = (const float*)d_in[1];
    const float* Wan1 = (const float*)d_in[2];  const float* ban1 = (const float*)d_in[3];
    const float* Wan2 = (const float*)d_in[4];  const float* ban2 = (const float*)d_in[5];
    const float* Wln1 = (const float*)d_in[6];  const float* bln1 = (const float*)d_in[7];
    const float* Wln2 = (const float*)d_in[8];  const float* bln2 = (const float*)d_in[9];
    const float* Wae1 = (const float*)d_in[10]; const float* bae1 = (const float*)d_in[11];
    const float* Wae2 = (const float*)d_in[12]; const float* bae2 = (const float*)d_in[13];
    const float* Wle1 = (const float*)d_in[14]; const float* ble1 = (const float*)d_in[15];
    const float* Wle2 = (const float*)d_in[16]; const float* ble2 = (const float*)d_in[17];

    char* ws = (char*)d_ws;
    size_t o = 0;
    auto alloc = [&](size_t bytes) -> void* {
        void* r = ws + o;
        o += (bytes + 255) & ~(size_t)255;
        return r;
    };
    ushort_t* hn     = (ushort_t*)alloc((size_t)MROWS * 128 * 2);
    ushort_t* he     = (ushort_t*)alloc((size_t)MROWS * 64 * 2);
    float*    pnf    = (float*)alloc((size_t)2048 * 128 * 4);
    ushort_t* nodesb = (ushort_t*)alloc((size_t)2 * NN * 64 * 2);
    ushort_t* edgesb = (ushort_t*)alloc((size_t)MROWS * 32 * 2);
    int2*     ijt    = (int2*)alloc((size_t)NEDGE * 8);
    ushort_t* pan1 = (ushort_t*)alloc(160 * 256 * 2);
    ushort_t* pan2 = (ushort_t*)alloc(256 * 128 * 2);
    ushort_t* pae1 = (ushort_t*)alloc(96 * 128 * 2);
    ushort_t* pae2 = (ushort_t*)alloc(128 * 64 * 2);
    ushort_t* ple1 = (ushort_t*)alloc(96 * 96 * 2);
    ushort_t* ple2 = (ushort_t*)alloc(96 * 32 * 2);
    ushort_t* pln1 = (ushort_t*)alloc(192 * 192 * 2);
    ushort_t* pln2 = (ushort_t*)alloc(192 * 64 * 2);

    float* out_nodes = (float*)d_out;
    float* out_edges = (float*)d_out + 2 * NN * 64;

    k_pack<<<2678, 256, 0, stream>>>(Wan1, Wan2, Wae1, Wae2, Wle1, Wle2, Wln1, Wln2,
                                     nodes, edges,
                                     pan1, pan2, pae1, pae2, ple1, ple2, pln1, pln2,
                                     nodesb, edgesb, ijt, pnf);
    k_agg<<<2015, 512, 0, stream>>>(nodesb, edgesb, ijt,
                                    pan1, ban1, pan2, ban2,
                                    pae1, bae1, pae2, bae2, hn, he, pnf);
    k_fin<<<64 + 2015, 192, 0, stream>>>(pnf, nodesb, he, edgesb, ijt,
                                         pln1, bln1, pln2, bln2, out_nodes,
                                         ple1, ble1, ple2, ble2, out_edges);

    (void)in_sizes; (void)n_in; (void)out_size; (void)ws_size;
}

// Round 15
// 165.486 us; speedup vs baseline: 1.5321x; 1.0187x over previous
//
#include <hip/hip_runtime.h>
#include <cstdint>

#define NN    1024
#define MM    32
#define NEDGE 32240
#define MROWS 64480   // 2*NEDGE
#define PX    168     // X tile pitch (ushorts)
#define PST   392     // unified stage pitch: 256 (H1n) + 128 (H1e) + 8 pad

typedef unsigned short ushort_t;

typedef __bf16 bf16x8 __attribute__((ext_vector_type(8)));
typedef float  floatx4 __attribute__((ext_vector_type(4)));

__device__ __forceinline__ float b2f(ushort_t u) {
    union { unsigned int i; float f; } v; v.i = ((unsigned int)u) << 16; return v.f;
}
__device__ __forceinline__ ushort_t f2b(float f) {
    unsigned int u = __builtin_bit_cast(unsigned int, f);
    u = (u + 0x7FFFu + ((u >> 16) & 1u)) >> 16;
    return (ushort_t)u;
}
// K(i): number of edges before node i
__device__ __forceinline__ int edge_base(int i) {
    return (i <= MM) ? ((i * (i - 1)) >> 1) : (496 + (i - MM) * MM);
}
// edge id e -> (dest i, src j)   [validated round 3; used only in pack]
__device__ __forceinline__ void edge_ij(int e, int& i, int& j) {
    if (e < 496) {
        i = (int)((1.0f + sqrtf(8.0f * (float)e + 1.0f)) * 0.5f);
        while (((i * (i - 1)) >> 1) > e) --i;
        while (((i * (i + 1)) >> 1) <= e) ++i;
        j = e - ((i * (i - 1)) >> 1);
    } else {
        int q = e - 496;
        i = MM + (q >> 5);
        j = i - MM + (q & 31);
    }
}

// ---------------- pack: weight transpose + nodes/edges bf16 + ij table (R11, proven) ----------------
__global__ __launch_bounds__(256) void k_pack(
        const float* an1, const float* an2, const float* ae1, const float* ae2,
        const float* le1, const float* le2, const float* ln1, const float* ln2,
        const float* nodes, const float* edges,
        ushort_t* pan1, ushort_t* pan2, ushort_t* pae1, ushort_t* pae2,
        ushort_t* ple1, ushort_t* ple2, ushort_t* pln1, ushort_t* pln2,
        ushort_t* nodesb, ushort_t* edgesb, int2* ijt) {
    __shared__ float tile[32][33];
    const int bid = blockIdx.x;
    const int tid = threadIdx.x;
    if (bid < 152) {
        const float* s; ushort_t* d; int K, N, t;
        if (bid < 40)       { s = an1; d = pan1; K = 160; N = 256; t = bid;       }
        else if (bid < 72)  { s = an2; d = pan2; K = 256; N = 128; t = bid - 40;  }
        else if (bid < 84)  { s = ae1; d = pae1; K = 96;  N = 128; t = bid - 72;  }
        else if (bid < 92)  { s = ae2; d = pae2; K = 128; N = 64;  t = bid - 84;  }
        else if (bid < 101) { s = le1; d = ple1; K = 96;  N = 96;  t = bid - 92;  }
        else if (bid < 104) { s = le2; d = ple2; K = 96;  N = 32;  t = bid - 101; }
        else if (bid < 140) { s = ln1; d = pln1; K = 192; N = 192; t = bid - 104; }
        else                { s = ln2; d = pln2; K = 192; N = 64;  t = bid - 140; }
        int ntn = N >> 5;
        int tk = t / ntn, tn = t - tk * ntn;
        int k0 = tk * 32, n0 = tn * 32;
        int tx = tid & 31, ty = tid >> 5;
#pragma unroll
        for (int m = 0; m < 4; ++m)
            tile[ty + m * 8][tx] = s[(size_t)(k0 + ty + m * 8) * N + n0 + tx];
        __syncthreads();
#pragma unroll
        for (int m = 0; m < 4; ++m)
            d[(size_t)(n0 + ty + m * 8) * K + k0 + tx] = f2b(tile[tx][ty + m * 8]);
    } else if (bid < 280) {
        int i4 = (bid - 152) * 256 + tid;
        float4 v = ((const float4*)nodes)[i4];
        uint2 o;
        o.x = (unsigned)f2b(v.x) | ((unsigned)f2b(v.y) << 16);
        o.y = (unsigned)f2b(v.z) | ((unsigned)f2b(v.w) << 16);
        ((uint2*)nodesb)[i4] = o;
    } else if (bid < 2296) {
        int i4 = (bid - 280) * 256 + tid;
        if (i4 < 515840) {
            float4 v = ((const float4*)edges)[i4];
            uint2 o;
            o.x = (unsigned)f2b(v.x) | ((unsigned)f2b(v.y) << 16);
            o.y = (unsigned)f2b(v.z) | ((unsigned)f2b(v.w) << 16);
            ((uint2*)edgesb)[i4] = o;
        }
    } else {
        int e = (bid - 2296) * 256 + tid;
        if (e < NEDGE) { int i, j; edge_ij(e, i, j); ijt[e] = make_int2(i, j); }
    }
}

// ---------------- agg: R11 body, separate output-stage LDS (3 barriers instead of 4) ----------------
__global__ __launch_bounds__(512, 2) void k_agg(
        const ushort_t* __restrict__ nodesb, const ushort_t* __restrict__ edgesb,
        const int2* __restrict__ ijt,
        const ushort_t* __restrict__ pan1, const float* __restrict__ ban1,
        const ushort_t* __restrict__ pan2, const float* __restrict__ ban2,
        const ushort_t* __restrict__ pae1, const float* __restrict__ bae1,
        const ushort_t* __restrict__ pae2, const float* __restrict__ bae2,
        ushort_t* __restrict__ hn, ushort_t* __restrict__ he) {
    __shared__ alignas(16) ushort_t X[32 * PX];     // X tile
    __shared__ alignas(16) ushort_t H[32 * PST];    // H1 tile [H1n 0..255 | H1e 256..383]
    __shared__ alignas(16) ushort_t SO[32 * 136];   // hn output stage (own buffer)
    __shared__ alignas(16) ushort_t TO[32 * 72];    // he output stage (own buffer)
    const int tid = threadIdx.x;
    const int w = tid >> 6, l = tid & 63, lrow = l & 15, lq = l >> 4;
    const int mt = blockIdx.x;
    floatx4 zero = {0.f, 0.f, 0.f, 0.f};

    // stage-1 B fragments (before gather for latency overlap)
    bf16x8 B0[5], B1[5], B2[3];
#pragma unroll
    for (int kt = 0; kt < 5; ++kt) {
        B0[kt] = *(const bf16x8*)(pan1 + (size_t)(16 * w + lrow) * 160 + kt * 32 + lq * 8);
        B1[kt] = *(const bf16x8*)(pan1 + (size_t)(16 * (w + 8) + lrow) * 160 + kt * 32 + lq * 8);
    }
#pragma unroll
    for (int kt = 0; kt < 3; ++kt)
        B2[kt] = *(const bf16x8*)(pae1 + (size_t)(16 * w + lrow) * 96 + kt * 32 + lq * 8);
    float c0 = ban1[16 * w + lrow];
    float c1 = ban1[16 * (w + 8) + lrow];
    float c2 = bae1[16 * w + lrow];

    // gather: wave w rows w*4..w*4+3, coalesced segments (R8/R11 proven idiom)
#pragma unroll
    for (int k = 0; k < 4; ++k) {
        int rr = w * 4 + k;
        int r = mt * 32 + rr;
        int off = (r >= NEDGE) ? 1 : 0;
        int2 ij = ijt[r - off * NEDGE];
        int bN = off * NN;
        unsigned* xr = (unsigned*)(X + rr * PX);
        const unsigned* nj = (const unsigned*)(nodesb + (size_t)(bN + ij.y) * 64);
        const unsigned* ni = (const unsigned*)(nodesb + (size_t)(bN + ij.x) * 64);
        const unsigned* eb = (const unsigned*)(edgesb + (size_t)r * 32);
        if (l < 32) { xr[l] = nj[l]; xr[48 + l] = ni[l]; }
        else        xr[l] = eb[l - 32];
    }
    __syncthreads();                                 // barrier 1: gather -> stage1

    // stage 1: A shared per s across the wave's 3 tiles
#pragma unroll
    for (int s = 0; s < 2; ++s) {
        bf16x8 A[5];
#pragma unroll
        for (int kt = 0; kt < 5; ++kt)
            A[kt] = *(const bf16x8*)&X[(s * 16 + lrow) * PX + kt * 32 + lq * 8];
        floatx4 a0 = zero, a1 = zero, a2 = zero;
#pragma unroll
        for (int kt = 0; kt < 5; ++kt) {
            a0 = __builtin_amdgcn_mfma_f32_16x16x32_bf16(A[kt], B0[kt], a0, 0, 0, 0);
            a1 = __builtin_amdgcn_mfma_f32_16x16x32_bf16(A[kt], B1[kt], a1, 0, 0, 0);
        }
#pragma unroll
        for (int kt = 0; kt < 3; ++kt)
            a2 = __builtin_amdgcn_mfma_f32_16x16x32_bf16(A[kt], B2[kt], a2, 0, 0, 0);
#pragma unroll
        for (int r_ = 0; r_ < 4; ++r_) {
            int row = (s * 16 + lq * 4 + r_) * PST;
            H[row + 16 * w + lrow]       = f2b(fmaxf(a0[r_] + c0, 0.f));
            H[row + 128 + 16 * w + lrow] = f2b(fmaxf(a1[r_] + c1, 0.f));
            H[row + 256 + 16 * w + lrow] = f2b(fmaxf(a2[r_] + c2, 0.f));
        }
    }

    // stage-2 B fragments issued BEFORE barrier 2 (LDS-independent; overlap with barrier wait)
    bf16x8 D0[8], D1[8], E[4];
    float d0 = 0.f, d1 = 0.f, d2 = 0.f;
    if (w < 4) {
#pragma unroll
        for (int kt = 0; kt < 8; ++kt) {
            D0[kt] = *(const bf16x8*)(pan2 + (size_t)(16 * w + lrow) * 256 + kt * 32 + lq * 8);
            D1[kt] = *(const bf16x8*)(pan2 + (size_t)(16 * (w + 4) + lrow) * 256 + kt * 32 + lq * 8);
        }
        d0 = ban2[16 * w + lrow];
        d1 = ban2[16 * (w + 4) + lrow];
    } else {
        int u = w - 4;
#pragma unroll
        for (int kt = 0; kt < 4; ++kt)
            E[kt] = *(const bf16x8*)(pae2 + (size_t)(16 * u + lrow) * 128 + kt * 32 + lq * 8);
        d2 = bae2[16 * u + lrow];
    }
    __syncthreads();                                 // barrier 2: stage1 -> stage2

    // stage 2 compute + fragment staging into OWN buffers (no barrier needed before staging)
    if (w < 4) {
#pragma unroll
        for (int s = 0; s < 2; ++s) {
            floatx4 a0 = zero, a1 = zero;
#pragma unroll
            for (int kt = 0; kt < 8; ++kt) {
                bf16x8 a = *(const bf16x8*)&H[(s * 16 + lrow) * PST + kt * 32 + lq * 8];
                a0 = __builtin_amdgcn_mfma_f32_16x16x32_bf16(a, D0[kt], a0, 0, 0, 0);
                a1 = __builtin_amdgcn_mfma_f32_16x16x32_bf16(a, D1[kt], a1, 0, 0, 0);
            }
#pragma unroll
            for (int r_ = 0; r_ < 4; ++r_) {
                int row = (s * 16 + lq * 4 + r_) * 136;
                SO[row + 16 * w + lrow]      = f2b(fmaxf(a0[r_] + d0, 0.f));
                SO[row + 64 + 16 * w + lrow] = f2b(fmaxf(a1[r_] + d1, 0.f));
            }
        }
    } else {
        int u = w - 4;
#pragma unroll
        for (int s = 0; s < 2; ++s) {
            floatx4 a2 = zero;
#pragma unroll
            for (int kt = 0; kt < 4; ++kt) {
                bf16x8 a = *(const bf16x8*)&H[(s * 16 + lrow) * PST + 256 + kt * 32 + lq * 8];
                a2 = __builtin_amdgcn_mfma_f32_16x16x32_bf16(a, E[kt], a2, 0, 0, 0);
            }
#pragma unroll
            for (int r_ = 0; r_ < 4; ++r_)
                TO[(s * 16 + lq * 4 + r_) * 72 + 16 * u + lrow] = f2b(fmaxf(a2[r_] + d2, 0.f));
        }
    }
    __syncthreads();                                 // barrier 3: staging -> stores

    // dense coalesced stores: hn 32 rows x 16 uint4, he 32 x 8
    {
        int row = tid >> 4, c = tid & 15;
        ((uint4*)(hn + (size_t)(mt * 32 + row) * 128))[c] = *(const uint4*)&SO[row * 136 + c * 8];
        if (tid < 256) {
            int row2 = tid >> 3, c2 = tid & 7;
            ((uint4*)(he + (size_t)(mt * 32 + row2) * 64))[c2] = *(const uint4*)&TO[row2 * 72 + c2 * 8];
        }
    }
}

// ---------------- mid: pn = window-parallel mean(hn) | pre = prefix-mean(he) (R11, proven) ----------------
__global__ __launch_bounds__(256) void k_mid(
        const ushort_t* __restrict__ hn, const ushort_t* __restrict__ he,
        ushort_t* __restrict__ pn, ushort_t* __restrict__ pre) {
    const int tid = threadIdx.x;
    if (blockIdx.x < 2048) {
        int ri = blockIdx.x;
        int b = ri >> 10, i = ri & 1023;
        int t = min(i, MM);
        int base = b * NEDGE + edge_base(i);
        int c = tid & 63, g = tid >> 6;
        float s0 = 0.f, s1 = 0.f;
        for (int p = g; p < t; p += 4) {
            unsigned u = ((const unsigned*)(hn + (size_t)(base + p) * 128))[c];
            s0 += b2f((ushort_t)(u & 0xffff));
            s1 += b2f((ushort_t)(u >> 16));
        }
        __shared__ float red[4][128];
        red[g][c * 2] = s0; red[g][c * 2 + 1] = s1;
        __syncthreads();
        if (tid < 64) {
            float inv = 1.0f / (float)max(t, 1);
            float a0 = (red[0][tid * 2] + red[1][tid * 2] + red[2][tid * 2] + red[3][tid * 2]) * inv;
            float a1 = (red[0][tid * 2 + 1] + red[1][tid * 2 + 1] + red[2][tid * 2 + 1] + red[3][tid * 2 + 1]) * inv;
            ((unsigned*)(pn + (size_t)ri * 128))[tid] = (unsigned)f2b(a0) | ((unsigned)f2b(a1) << 16);
        }
    } else {
        int bi = blockIdx.x - 2048;
        int b = bi >> 10, i = bi & 1023;
        int t = min(i, MM);
        if (t == 0) return;
        int base = b * NEDGE + edge_base(i);
        __shared__ alignas(16) ushort_t hw[32 * 64];
        for (int u = tid; u < t * 8; u += 256)
            ((uint4*)hw)[u] = ((const uint4*)he)[(size_t)base * 8 + u];
        __syncthreads();
        if (tid < 64) {
            float run = 0.f;
            for (int p = 0; p < t; ++p) {
                float v = (p == 0) ? 0.f : run / (float)p;
                pre[(size_t)(base + p) * 64 + tid] = f2b(v);
                run += b2f(hw[p * 64 + tid]);
            }
        }
    }
}

// ---------------- final: node MLP ([pn|nodesb] 192->192->64) | le12 ([pre|edgesb] 96->96->32) (R11) ----------------
__global__ __launch_bounds__(192) void k_final(
        const ushort_t* __restrict__ pn, const ushort_t* __restrict__ nodesb,
        const ushort_t* __restrict__ pln1, const float* __restrict__ bln1,
        const ushort_t* __restrict__ pln2, const float* __restrict__ bln2,
        float* __restrict__ out_nodes,
        const ushort_t* __restrict__ pre, const ushort_t* __restrict__ edgesb,
        const ushort_t* __restrict__ ple1, const float* __restrict__ ble1,
        const ushort_t* __restrict__ ple2, const float* __restrict__ ble2,
        float* __restrict__ out_edges) {
    __shared__ alignas(16) ushort_t LA[32 * 200];
    __shared__ alignas(16) ushort_t LB[32 * 200];
    const int tid = threadIdx.x;
    const int w = tid >> 6, l = tid & 63, lrow = l & 15, lq = l >> 4;
    floatx4 zero = {0.f, 0.f, 0.f, 0.f};

    if (blockIdx.x < 64) {
        int tile = blockIdx.x;
        for (int u = tid; u < 768; u += 192) {        // 32 rows x 24 uint4 chunks
            int row = u / 24, c = u - row * 24;
            int r = tile * 32 + row;
            const uint4* src = (c < 16) ? ((const uint4*)(pn + (size_t)r * 128) + c)
                                        : ((const uint4*)(nodesb + (size_t)r * 64) + (c - 16));
            *(uint4*)&LA[row * 200 + c * 8] = *src;
        }
        bf16x8 f1[6][4]; float v1[4];
#pragma unroll
        for (int kt = 0; kt < 6; ++kt)
#pragma unroll
            for (int nt = 0; nt < 4; ++nt)
                f1[kt][nt] = *(const bf16x8*)(pln1 + (size_t)(w * 64 + nt * 16 + lrow) * 192 + kt * 32 + lq * 8);
#pragma unroll
        for (int nt = 0; nt < 4; ++nt) v1[nt] = bln1[w * 64 + nt * 16 + lrow];
        __syncthreads();

        floatx4 acc[2][4];
#pragma unroll
        for (int s = 0; s < 2; ++s)
#pragma unroll
            for (int nt = 0; nt < 4; ++nt) acc[s][nt] = zero;
#pragma unroll
        for (int s = 0; s < 2; ++s)
#pragma unroll
            for (int kt = 0; kt < 6; ++kt) {
                bf16x8 a = *(const bf16x8*)&LA[(s * 16 + lrow) * 200 + kt * 32 + lq * 8];
#pragma unroll
                for (int nt = 0; nt < 4; ++nt)
                    acc[s][nt] = __builtin_amdgcn_mfma_f32_16x16x32_bf16(a, f1[kt][nt], acc[s][nt], 0, 0, 0);
            }
#pragma unroll
        for (int s = 0; s < 2; ++s)
#pragma unroll
            for (int nt = 0; nt < 4; ++nt) {
                int col = w * 64 + nt * 16 + lrow;
#pragma unroll
                for (int r_ = 0; r_ < 4; ++r_)
                    LB[(s * 16 + lq * 4 + r_) * 200 + col] = f2b(fmaxf(acc[s][nt][r_] + v1[nt], 0.f));
            }
        bf16x8 f2[6][2]; float v2[2] = {0.f, 0.f};
        if (w < 2) {
#pragma unroll
            for (int kt = 0; kt < 6; ++kt)
#pragma unroll
                for (int nt = 0; nt < 2; ++nt)
                    f2[kt][nt] = *(const bf16x8*)(pln2 + (size_t)(w * 32 + nt * 16 + lrow) * 192 + kt * 32 + lq * 8);
#pragma unroll
            for (int nt = 0; nt < 2; ++nt) v2[nt] = bln2[w * 32 + nt * 16 + lrow];
        }
        __syncthreads();
        if (w < 2) {
            floatx4 a2[2][2];
#pragma unroll
            for (int s = 0; s < 2; ++s) { a2[s][0] = zero; a2[s][1] = zero; }
#pragma unroll
            for (int s = 0; s < 2; ++s)
#pragma unroll
                for (int kt = 0; kt < 6; ++kt) {
                    bf16x8 a = *(const bf16x8*)&LB[(s * 16 + lrow) * 200 + kt * 32 + lq * 8];
#pragma unroll
                    for (int nt = 0; nt < 2; ++nt)
                        a2[s][nt] = __builtin_amdgcn_mfma_f32_16x16x32_bf16(a, f2[kt][nt], a2[s][nt], 0, 0, 0);
                }
#pragma unroll
            for (int s = 0; s < 2; ++s)
#pragma unroll
                for (int nt = 0; nt < 2; ++nt) {
                    int col = w * 32 + nt * 16 + lrow;
#pragma unroll
                    for (int r_ = 0; r_ < 4; ++r_)
                        out_nodes[(size_t)(tile * 32 + s * 16 + lq * 4 + r_) * 64 + col] =
                            fmaxf(a2[s][nt][r_] + v2[nt], 0.f);
                }
        }
    } else {
        int mt = blockIdx.x - 64;
        // stage [pre(8) | edgesb(4)] chunks per row, pitch 104
        for (int u = tid; u < 384; u += 192) {
            int row = u / 12, c = u - row * 12;
            int r = mt * 32 + row;
            const uint4* src = (c < 8) ? ((const uint4*)(pre + (size_t)r * 64) + c)
                                       : ((const uint4*)(edgesb + (size_t)r * 32) + (c - 8));
            *(uint4*)&LA[row * 104 + c * 8] = *src;
        }
        bf16x8 fb1[3][2]; float v1[2];
#pragma unroll
        for (int kt = 0; kt < 3; ++kt)
#pragma unroll
            for (int nt = 0; nt < 2; ++nt)
                fb1[kt][nt] = *(const bf16x8*)(ple1 + (size_t)(w * 32 + nt * 16 + lrow) * 96 + kt * 32 + lq * 8);
#pragma unroll
        for (int nt = 0; nt < 2; ++nt) v1[nt] = ble1[w * 32 + nt * 16 + lrow];
        bf16x8 fb2[3]; float v2 = 0.f;
        if (w < 2) {
#pragma unroll
            for (int kt = 0; kt < 3; ++kt)
                fb2[kt] = *(const bf16x8*)(ple2 + (size_t)(w * 16 + lrow) * 96 + kt * 32 + lq * 8);
            v2 = ble2[w * 16 + lrow];
        }
        __syncthreads();

        floatx4 acc[2][2];
#pragma unroll
        for (int s = 0; s < 2; ++s) { acc[s][0] = zero; acc[s][1] = zero; }
#pragma unroll
        for (int s = 0; s < 2; ++s)
#pragma unroll
            for (int kt = 0; kt < 3; ++kt) {
                bf16x8 a = *(const bf16x8*)&LA[(s * 16 + lrow) * 104 + kt * 32 + lq * 8];
#pragma unroll
                for (int nt = 0; nt < 2; ++nt)
                    acc[s][nt] = __builtin_amdgcn_mfma_f32_16x16x32_bf16(a, fb1[kt][nt], acc[s][nt], 0, 0, 0);
            }
#pragma unroll
        for (int s = 0; s < 2; ++s)
#pragma unroll
            for (int nt = 0; nt < 2; ++nt) {
                int col = w * 32 + nt * 16 + lrow;
#pragma unroll
                for (int r_ = 0; r_ < 4; ++r_)
                    LB[(s * 16 + lq * 4 + r_) * 104 + col] = f2b(fmaxf(acc[s][nt][r_] + v1[nt], 0.f));
            }
        __syncthreads();
        if (w < 2) {
            floatx4 a2[2] = {zero, zero};
#pragma unroll
            for (int s = 0; s < 2; ++s)
#pragma unroll
                for (int kt = 0; kt < 3; ++kt) {
                    bf16x8 a = *(const bf16x8*)&LB[(s * 16 + lrow) * 104 + kt * 32 + lq * 8];
                    a2[s] = __builtin_amdgcn_mfma_f32_16x16x32_bf16(a, fb2[kt], a2[s], 0, 0, 0);
                }
#pragma unroll
            for (int s = 0; s < 2; ++s) {
                int col = w * 16 + lrow;
#pragma unroll
                for (int r_ = 0; r_ < 4; ++r_)
                    out_edges[(size_t)(mt * 32 + s * 16 + lq * 4 + r_) * 32 + col] = fmaxf(a2[s][r_] + v2, 0.f);
            }
        }
    }
}

extern "C" void kernel_launch(void* const* d_in, const int* in_sizes, int n_in,
                              void* d_out, int out_size, void* d_ws, size_t ws_size,
                              hipStream_t stream) {
    const float* nodes = (const float*)d_in[0];
    const float* edges = (const float*)d_in[1];
    const float* Wan1 = (const float*)d_in[2];  const float* ban1 = (const float*)d_in[3];
    const float* Wan2 = (const float*)d_in[4];  const float* ban2 = (const float*)d_in[5];
    const float* Wln1 = (const float*)d_in[6];  const float* bln1 = (const float*)d_in[7];
    const float* Wln2 = (const float*)d_in[8];  const float* bln2 = (const float*)d_in[9];
    const float* Wae1 = (const float*)d_in[10]; const float* bae1 = (const float*)d_in[11];
    const float* Wae2 = (const float*)d_in[12]; const float* bae2 = (const float*)d_in[13];
    const float* Wle1 = (const float*)d_in[14]; const float* ble1 = (const float*)d_in[15];
    const float* Wle2 = (const float*)d_in[16]; const float* ble2 = (const float*)d_in[17];

    char* ws = (char*)d_ws;
    size_t o = 0;
    auto alloc = [&](size_t bytes) -> void* {
        void* r = ws + o;
        o += (bytes + 255) & ~(size_t)255;
        return r;
    };
    ushort_t* hn     = (ushort_t*)alloc((size_t)MROWS * 128 * 2);
    ushort_t* he     = (ushort_t*)alloc((size_t)MROWS * 64 * 2);
    ushort_t* pre    = (ushort_t*)alloc((size_t)MROWS * 64 * 2);
    ushort_t* pn     = (ushort_t*)alloc((size_t)2048 * 128 * 2);
    ushort_t* nodesb = (ushort_t*)alloc((size_t)2 * NN * 64 * 2);
    ushort_t* edgesb = (ushort_t*)alloc((size_t)MROWS * 32 * 2);
    int2*     ijt    = (int2*)alloc((size_t)NEDGE * 8);
    ushort_t* pan1 = (ushort_t*)alloc(160 * 256 * 2);
    ushort_t* pan2 = (ushort_t*)alloc(256 * 128 * 2);
    ushort_t* pae1 = (ushort_t*)alloc(96 * 128 * 2);
    ushort_t* pae2 = (ushort_t*)alloc(128 * 64 * 2);
    ushort_t* ple1 = (ushort_t*)alloc(96 * 96 * 2);
    ushort_t* ple2 = (ushort_t*)alloc(96 * 32 * 2);
    ushort_t* pln1 = (ushort_t*)alloc(192 * 192 * 2);
    ushort_t* pln2 = (ushort_t*)alloc(192 * 64 * 2);

    float* out_nodes = (float*)d_out;
    float* out_edges = (float*)d_out + 2 * NN * 64;

    k_pack<<<2422, 256, 0, stream>>>(Wan1, Wan2, Wae1, Wae2, Wle1, Wle2, Wln1, Wln2,
                                     nodes, edges,
                                     pan1, pan2, pae1, pae2, ple1, ple2, pln1, pln2,
                                     nodesb, edgesb, ijt);
    k_agg<<<2015, 512, 0, stream>>>(nodesb, edgesb, ijt,
                                    pan1, ban1, pan2, ban2,
                                    pae1, bae1, pae2, bae2, hn, he);
    k_mid<<<4096, 256, 0, stream>>>(hn, he, pn, pre);
    k_final<<<64 + 2015, 192, 0, stream>>>(pn, nodesb, pln1, bln1, pln2, bln2, out_nodes,
                                           pre, edgesb, ple1, ble1, ple2, ble2, out_edges);

    (void)in_sizes; (void)n_in; (void)out_size; (void)ws_size;
}